// Round 12
// baseline (317.856 us; speedup 1.0000x reference)
//
#include <hip/hip_runtime.h>
#include <hip/hip_bf16.h>

// Fused retention block, round 12: r11 + AGPR-peak split (QKV 2-pass, FFN1
// 2-half straight-line) to seat 4 blocks/CU + setprio + packed V^T writes.
// grid = 8192 (one block per n), 512 threads = 8 waves (wave w = head w in attn).
// d_ws: [0,98304) QKV bf16 frags | [98304,229376) w1 bf16 frags |
//       [229376,294912) w2 FP8 frags | [360448,364544) rot table f32x2[32][16].
// LDS pool 39424 B. Lifetime map (bytes):
//   XB  [0,8704)      bf16[32][136] x tile         (dead after LN1 reads)
//   QB  [8704,17408)  bf16[32][136] rot Q          (dead after attn frag preload)
//   KB  [17408,26112) bf16[32][136] rot K          (dead after attn frag preload)
//   VT  [26112,35328) bf16 8x[16][36] V^T          (dead after attn frag preload)
//   TAB [35328,39424) f32x2[512] rot table         (dead after QKV epilogue)
//   P   [8704,27136)  bf16 8x[32][36] over QB/KB/VT0, after mid-attn barrier
//   OO  [27136,35840) bf16[32][136]: attn-out -> LN1-out(in place) -> O2(in place)
//   H   [0,16640)     fp8[32][520] over XB/QB (written in FFN1, after LN1 barrier)
// Barriers: stage | QKV | mid-attn | attn | LN1 | FFN1 | FFN2 = 7

#define NN 8192
#define BS 32
#define CC 128
#define HH 8
#define DD 16
#define FF 512
#define QS 129   // fp32 fallback stride

typedef __attribute__((ext_vector_type(8))) short bf16x8;
typedef __attribute__((ext_vector_type(4))) float f32x4;
typedef __attribute__((ext_vector_type(4))) unsigned int u32x4;
typedef __attribute__((ext_vector_type(2))) unsigned int u32x2;

#define XB_H 0
#define QB_H 4352
#define KB_H 8704
#define VT_H 13056
#define TAB_F 8832
#define P_H 4352
#define P_HEAD 1152
#define P_STR 36
#define OO_H 13568
#define H_STR 520
#define W2FP8_OFF 229376
#define LDS_BYTES 39424

__device__ inline unsigned short f2bf(float f) {
  return __builtin_bit_cast(unsigned short, __float2bfloat16(f));
}
__device__ inline unsigned pk2bf(float lo, float hi) {
  return (unsigned)f2bf(lo) | ((unsigned)f2bf(hi) << 16);
}
__device__ inline float bf2f(unsigned short h) {
  unsigned u = ((unsigned)h) << 16;
  return __builtin_bit_cast(float, u);
}

// f32 -> fp8 e4m3fn (OCP), software fallback
__device__ inline unsigned char f2fp8_sw(float x) {
  unsigned u = __builtin_bit_cast(unsigned, x);
  unsigned sign = (u >> 31) << 7;
  float ax = fabsf(x);
  if (!(ax >= 0.015625f)) {
    int q = (int)(ax * 512.0f + 0.5f);
    if (q > 7) return (unsigned char)(sign | 8);
    return (unsigned char)(sign | q);
  }
  if (ax > 448.0f) ax = 448.0f;
  unsigned au = __builtin_bit_cast(unsigned, ax);
  int exp = (int)((au >> 23) & 0xff) - 127;
  unsigned m3 = ((au & 0x7fffff) + 0x80000) >> 20;
  if (m3 >= 8) { m3 = 0; exp += 1; }
  if (exp > 8) return (unsigned char)(sign | 0x7e);
  return (unsigned char)(sign | ((unsigned)(exp + 7) << 3) | m3);
}
__device__ inline unsigned char f2fp8(float x) {
#if defined(__has_builtin) && __has_builtin(__builtin_amdgcn_cvt_pk_fp8_f32)
  return (unsigned char)(__builtin_amdgcn_cvt_pk_fp8_f32(x, x, 0, false) & 0xff);
#else
  return f2fp8_sw(x);
#endif
}
__device__ inline unsigned pack4fp8(float a, float b, float c, float d) {
#if defined(__has_builtin) && __has_builtin(__builtin_amdgcn_cvt_pk_fp8_f32)
  int r = __builtin_amdgcn_cvt_pk_fp8_f32(a, b, 0, false);
  r = __builtin_amdgcn_cvt_pk_fp8_f32(c, d, r, true);
  return (unsigned)r;
#else
  return (unsigned)f2fp8_sw(a) | ((unsigned)f2fp8_sw(b) << 8) |
         ((unsigned)f2fp8_sw(c) << 16) | ((unsigned)f2fp8_sw(d) << 24);
#endif
}

// ---------------------------------------------------------------------------
// Pack kernel (unchanged from r11).
// ---------------------------------------------------------------------------
__global__ void pack_weights(const float* __restrict__ wq, const float* __restrict__ wk,
                             const float* __restrict__ wv, const float* __restrict__ w1,
                             const float* __restrict__ w2, unsigned short* __restrict__ outp)
{
  const int id = blockIdx.x * 256 + threadIdx.x;
  if (id >= 23040) return;
  if (id >= 22528) {
    const int i = id - 22528;
    const int s = i >> 4, d = i & 15;
    const float a = exp2f(-1.89824462565f * (float)(d >> 1));
    const float ang = (float)s * a;
    float2* tab = (float2*)(outp + 180224);
    tab[i] = make_float2(sinf(ang), cosf(ang));
    return;
  }
  const int l = id & 63;
  const int chunk = id >> 6;
  if (chunk >= 224) {
    const int c2 = chunk - 224, ct = c2 >> 4, kk = c2 & 15;
    const int colbase = ct * 16 + (l & 15);
    const int k0 = kk * 32 + (l >> 4) * 8;
    float v[8];
    #pragma unroll
    for (int jj = 0; jj < 8; ++jj) v[jj] = w2[(size_t)(k0 + jj) * CC + colbase];
    u32x2 pw;
    pw[0] = pack4fp8(v[0], v[1], v[2], v[3]);
    pw[1] = pack4fp8(v[4], v[5], v[6], v[7]);
    *(u32x2*)((char*)outp + W2FP8_OFF + ((size_t)c2 * 64 + l) * 8) = pw;
    return;
  }
  const float* W; int ldw, colbase, k0;
  if (chunk < 96) {
    const int ct = chunk >> 2, kk = chunk & 3;
    W = (ct < 8) ? wq : (ct < 16) ? wk : wv;
    ldw = CC; colbase = (ct & 7) * 16 + (l & 15); k0 = kk * 32 + (l >> 4) * 8;
  } else {
    const int c2 = chunk - 96, ct = c2 >> 2, kk = c2 & 3;
    W = w1; ldw = FF; colbase = ct * 16 + (l & 15); k0 = kk * 32 + (l >> 4) * 8;
  }
  unsigned int o[4];
  #pragma unroll
  for (int jj = 0; jj < 4; ++jj)
    o[jj] = pk2bf(W[(size_t)(k0 + 2 * jj) * ldw + colbase],
                  W[(size_t)(k0 + 2 * jj + 1) * ldw + colbase]);
  *(u32x4*)(outp + (size_t)id * 8) = (u32x4){o[0], o[1], o[2], o[3]};
}

__global__ __launch_bounds__(512, 6) void fused_mfma(
    const float* __restrict__ x,
    const float* __restrict__ bq, const float* __restrict__ bk, const float* __restrict__ bv,
    const float* __restrict__ ln1g, const float* __restrict__ ln1b,
    const float* __restrict__ b1, const float* __restrict__ b2,
    const float* __restrict__ ln2g, const float* __restrict__ ln2b,
    const unsigned short* __restrict__ wpack,
    const float2* __restrict__ rott,
    float* __restrict__ out)
{
  extern __shared__ char smem[];
  float* ldsf = (float*)smem;
  unsigned short* ldsh = (unsigned short*)smem;
  const int n = blockIdx.x;
  const int t = threadIdx.x;
  const int w = t >> 6;
  const int l = t & 63;
  const int lr = l & 15;
  const int lg = l >> 4;

  // ---------------- stage X -> bf16 LDS + rot table ------------------------
  {
    const int s = t >> 4, c0 = (t & 15) * 8;
    const float* xp = x + ((size_t)s * NN + n) * CC + c0;
    const float4 v0 = *(const float4*)xp;
    const float4 v1 = *(const float4*)(xp + 4);
    u32x4 pk;
    pk[0] = pk2bf(v0.x, v0.y);
    pk[1] = pk2bf(v0.z, v0.w);
    pk[2] = pk2bf(v1.x, v1.y);
    pk[3] = pk2bf(v1.z, v1.w);
    *(u32x4*)(ldsh + XB_H + s * 136 + c0) = pk;
    ((float2*)(ldsf + TAB_F))[t] = rott[t];
  }
  __syncthreads();

  // ---------------- QKV MFMA, 2 row-tile passes (12 AGPR each) -------------
  {
    const int pd = (lr < 8) ? (2 * lr + 1) : (2 * lr - 16);
    const float sgn = (lr < 8) ? -1.0f : 1.0f;
    const int psrc = (l & 48) | pd;
    #pragma unroll
    for (int rt = 0; rt < 2; ++rt) {
      f32x4 acc[3];
      #pragma unroll
      for (int c = 0; c < 3; ++c) {
        const int ct = 3 * w + c;
        const int col = (ct & 7) * 16 + lr;
        const float* bb = (ct < 8) ? bq : (ct < 16) ? bk : bv;
        const float b = bb[col];
        acc[c] = (f32x4){b, b, b, b};
      }
      __builtin_amdgcn_s_setprio(1);
      #pragma unroll
      for (int kk = 0; kk < 4; ++kk) {
        const bf16x8 a0 = *(const bf16x8*)(ldsh + XB_H + (rt * 16 + lr) * 136 + kk * 32 + lg * 8);
        #pragma unroll
        for (int c = 0; c < 3; ++c) {
          const int ct = 3 * w + c;
          const bf16x8 b = *(const bf16x8*)(wpack + ((size_t)(ct * 4 + kk) * 64 + l) * 8);
          acc[c] = __builtin_amdgcn_mfma_f32_16x16x32_bf16(a0, b, acc[c], 0, 0, 0);
        }
      }
      __builtin_amdgcn_s_setprio(0);
      float sn[4], cs[4];
      if (3 * w < 16) {
        #pragma unroll
        for (int e = 0; e < 4; ++e) {
          const int row = rt * 16 + lg * 4 + e;
          const float2 tc = ((const float2*)(ldsf + TAB_F))[row * 16 + lr];
          sn[e] = tc.x;
          cs[e] = tc.y;
        }
      }
      #pragma unroll
      for (int c = 0; c < 3; ++c) {
        const int ct = 3 * w + c;
        if (ct < 16) {
          const int dst = (ct < 8) ? QB_H : KB_H;
          const int colbase = (ct & 7) * 16;
          #pragma unroll
          for (int e = 0; e < 4; ++e) {
            const float v = acc[c][e];
            const float pv = __shfl(v, psrc);
            const float r = v * cs[e] + sgn * pv * sn[e];
            ldsh[dst + (rt * 16 + lg * 4 + e) * 136 + colbase + lr] = f2bf(r);
          }
        } else {
          // V^T: packed 4-short write (e-contiguous)
          const int hv = ct - 16;
          u32x2 pw;
          pw[0] = pk2bf(acc[c][0], acc[c][1]);
          pw[1] = pk2bf(acc[c][2], acc[c][3]);
          *(u32x2*)(ldsh + VT_H + hv * 576 + lr * 36 + rt * 16 + lg * 4) = pw;
        }
      }
    }
  }
  __syncthreads();

  // ---------------- MFMA attention: wave w = head w ------------------------
  {
    const int h16 = w * 16;
    const float dec = log1pf(-exp2f(-(1.0f + 0.375f * (float)w)));
    const bf16x8 z = {};
    bf16x8 Ak[2], Bq[2];
    #pragma unroll
    for (int kt = 0; kt < 2; ++kt)
      Ak[kt] = (lg < 2) ? *(const bf16x8*)(ldsh + KB_H + (kt * 16 + lr) * 136 + h16 + lg * 8) : z;
    #pragma unroll
    for (int qt = 0; qt < 2; ++qt)
      Bq[qt] = (lg < 2) ? *(const bf16x8*)(ldsh + QB_H + (qt * 16 + lr) * 136 + h16 + lg * 8) : z;
    const bf16x8 Bv = *(const bf16x8*)(ldsh + VT_H + w * 576 + lr * 36 + lg * 8);
    __syncthreads();   // frags in regs; QB/KB/VT now reusable as P; OO writable

    f32x4 accs[2][2];
    __builtin_amdgcn_s_setprio(1);
    #pragma unroll
    for (int kt = 0; kt < 2; ++kt)
      #pragma unroll
      for (int qt = 0; qt < 2; ++qt) {
        #pragma unroll
        for (int e = 0; e < 4; ++e) {
          const int q = qt * 16 + lr;
          const int k = kt * 16 + lg * 4 + e;
          accs[kt][qt][e] = fabsf((float)(q - k)) * dec;
        }
        accs[kt][qt] = __builtin_amdgcn_mfma_f32_16x16x32_bf16(Ak[kt], Bq[qt], accs[kt][qt], 0, 0, 0);
      }
    __builtin_amdgcn_s_setprio(0);
    unsigned short* Pl = ldsh + P_H + w * P_HEAD;
    #pragma unroll
    for (int qt = 0; qt < 2; ++qt) {
      float mx = accs[0][qt][0];
      #pragma unroll
      for (int kt = 0; kt < 2; ++kt)
        #pragma unroll
        for (int e = 0; e < 4; ++e) mx = fmaxf(mx, accs[kt][qt][e]);
      mx = fmaxf(mx, __shfl_xor(mx, 16));
      mx = fmaxf(mx, __shfl_xor(mx, 32));
      float p[2][4];
      float sm = 0.0f;
      #pragma unroll
      for (int kt = 0; kt < 2; ++kt)
        #pragma unroll
        for (int e = 0; e < 4; ++e) { p[kt][e] = __expf(accs[kt][qt][e] - mx); sm += p[kt][e]; }
      sm += __shfl_xor(sm, 16);
      sm += __shfl_xor(sm, 32);
      const float inv = 1.0f / sm;
      #pragma unroll
      for (int kt = 0; kt < 2; ++kt) {
        u32x2 pw;
        pw[0] = pk2bf(p[kt][0] * inv, p[kt][1] * inv);
        pw[1] = pk2bf(p[kt][2] * inv, p[kt][3] * inv);
        *(u32x2*)(Pl + (qt * 16 + lr) * P_STR + kt * 16 + lg * 4) = pw;
      }
    }
    // PV
    __builtin_amdgcn_s_setprio(1);
    #pragma unroll
    for (int qt = 0; qt < 2; ++qt) {
      const bf16x8 Ap = *(const bf16x8*)(Pl + (qt * 16 + lr) * P_STR + lg * 8);
      f32x4 z4 = {0.0f, 0.0f, 0.0f, 0.0f};
      const f32x4 o = __builtin_amdgcn_mfma_f32_16x16x32_bf16(Ap, Bv, z4, 0, 0, 0);
      #pragma unroll
      for (int e = 0; e < 4; ++e)
        ldsh[OO_H + (qt * 16 + lg * 4 + e) * 136 + h16 + lr] = f2bf(o[e]);
    }
    __builtin_amdgcn_s_setprio(0);
  }
  __syncthreads();

  // ---------------- LN1(attn_out + x) -> bf16, in place over OO ------------
  {
    const int row = t >> 4, sub = t & 15;
    const unsigned short* Or = ldsh + OO_H + row * 136 + sub * 8;
    const unsigned short* Xr = ldsh + XB_H + row * 136 + sub * 8;
    float v[8];
    #pragma unroll
    for (int i = 0; i < 8; ++i) v[i] = bf2f(Or[i]) + bf2f(Xr[i]);
    float sum = 0.0f;
    #pragma unroll
    for (int i = 0; i < 8; ++i) sum += v[i];
    #pragma unroll
    for (int m = 1; m < 16; m <<= 1) sum += __shfl_xor(sum, m);
    const float mu = sum * (1.0f / 128.0f);
    float s2 = 0.0f;
    #pragma unroll
    for (int i = 0; i < 8; ++i) { const float d = v[i] - mu; s2 += d * d; }
    #pragma unroll
    for (int m = 1; m < 16; m <<= 1) s2 += __shfl_xor(s2, m);
    const float rstd = rsqrtf(s2 * (1.0f / 128.0f) + 1e-5f);
    u32x4 pk;
    #pragma unroll
    for (int i = 0; i < 4; ++i) {
      const int c = sub * 8 + 2 * i;
      pk[i] = pk2bf((v[2 * i] - mu) * rstd * ln1g[c] + ln1b[c],
                    (v[2 * i + 1] - mu) * rstd * ln1g[c + 1] + ln1b[c + 1]);
    }
    *(u32x4*)(ldsh + OO_H + row * 136 + sub * 8) = pk;
  }
  __syncthreads();

  // ---------------- FFN1: H fp8[32][520], two straight-line halves ---------
  {
    char* Hb = smem;   // H over dead XB/QB, [0,16640)
    // ---- half 0 (rows 0-15), 16 AGPR ----
    {
      f32x4 acc1[4];
      #pragma unroll
      for (int c = 0; c < 4; ++c) {
        const float b = b1[(4 * w + c) * 16 + lr];
        acc1[c] = (f32x4){b, b, b, b};
      }
      __builtin_amdgcn_s_setprio(1);
      #pragma unroll
      for (int kk = 0; kk < 4; ++kk) {
        const bf16x8 a = *(const bf16x8*)(ldsh + OO_H + lr * 136 + kk * 32 + lg * 8);
        #pragma unroll
        for (int c = 0; c < 4; ++c) {
          const int chunk = 96 + (4 * w + c) * 4 + kk;
          const bf16x8 b = *(const bf16x8*)(wpack + ((size_t)chunk * 64 + l) * 8);
          acc1[c] = __builtin_amdgcn_mfma_f32_16x16x32_bf16(a, b, acc1[c], 0, 0, 0);
        }
      }
      __builtin_amdgcn_s_setprio(0);
      #pragma unroll
      for (int c = 0; c < 4; ++c) {
        const int col = (4 * w + c) * 16 + lr;
        #pragma unroll
        for (int e = 0; e < 4; ++e)
          Hb[(lg * 4 + e) * H_STR + col] = (char)f2fp8(fmaxf(acc1[c][e], 0.0f));
      }
    }
    // ---- half 1 (rows 16-31), 16 AGPR ----
    {
      f32x4 acc1[4];
      #pragma unroll
      for (int c = 0; c < 4; ++c) {
        const float b = b1[(4 * w + c) * 16 + lr];
        acc1[c] = (f32x4){b, b, b, b};
      }
      __builtin_amdgcn_s_setprio(1);
      #pragma unroll
      for (int kk = 0; kk < 4; ++kk) {
        const bf16x8 a = *(const bf16x8*)(ldsh + OO_H + (16 + lr) * 136 + kk * 32 + lg * 8);
        #pragma unroll
        for (int c = 0; c < 4; ++c) {
          const int chunk = 96 + (4 * w + c) * 4 + kk;
          const bf16x8 b = *(const bf16x8*)(wpack + ((size_t)chunk * 64 + l) * 8);
          acc1[c] = __builtin_amdgcn_mfma_f32_16x16x32_bf16(a, b, acc1[c], 0, 0, 0);
        }
      }
      __builtin_amdgcn_s_setprio(0);
      #pragma unroll
      for (int c = 0; c < 4; ++c) {
        const int col = (4 * w + c) * 16 + lr;
        #pragma unroll
        for (int e = 0; e < 4; ++e)
          Hb[(16 + lg * 4 + e) * H_STR + col] = (char)f2fp8(fmaxf(acc1[c][e], 0.0f));
      }
    }
  }
  __syncthreads();

  // ---------------- FFN2 (fp8): O2 = H @ w2 + b2 + O1, in place over OO ----
  {
    const int col = w * 16 + lr;
    const float b = b2[col];
    f32x4 acc2[2];
    acc2[0] = (f32x4){b, b, b, b};
    acc2[1] = acc2[0];
    const char* Hb = smem;
    const char* W2 = (const char*)wpack + W2FP8_OFF;
    __builtin_amdgcn_s_setprio(1);
    #pragma unroll
    for (int kk = 0; kk < 16; ++kk) {
      const long a0 = *(const long*)(Hb + lr * H_STR + kk * 32 + lg * 8);
      const long a1 = *(const long*)(Hb + (16 + lr) * H_STR + kk * 32 + lg * 8);
      const long bb = *(const long*)(W2 + ((size_t)(w * 16 + kk) * 64 + l) * 8);
      acc2[0] = __builtin_amdgcn_mfma_f32_16x16x32_fp8_fp8(a0, bb, acc2[0], 0, 0, 0);
      acc2[1] = __builtin_amdgcn_mfma_f32_16x16x32_fp8_fp8(a1, bb, acc2[1], 0, 0, 0);
    }
    __builtin_amdgcn_s_setprio(0);
    #pragma unroll
    for (int p = 0; p < 2; ++p)
      #pragma unroll
      for (int e = 0; e < 4; ++e) {
        const int srow = p * 16 + lg * 4 + e;
        const int idx = OO_H + srow * 136 + col;
        const float res = bf2f(ldsh[idx]);
        ldsh[idx] = f2bf(acc2[p][e] + res);
      }
  }
  __syncthreads();

  // ---------------- LN2 (32 rows at once) + transposed store ---------------
  {
    const int row = t >> 4, sub = t & 15;
    const unsigned short* Or = ldsh + OO_H + row * 136 + sub * 8;
    float v[8];
    #pragma unroll
    for (int i = 0; i < 8; ++i) v[i] = bf2f(Or[i]);
    float sum = 0.0f;
    #pragma unroll
    for (int i = 0; i < 8; ++i) sum += v[i];
    #pragma unroll
    for (int m = 1; m < 16; m <<= 1) sum += __shfl_xor(sum, m);
    const float mu = sum * (1.0f / 128.0f);
    float s2 = 0.0f;
    #pragma unroll
    for (int i = 0; i < 8; ++i) { const float d = v[i] - mu; s2 += d * d; }
    #pragma unroll
    for (int m = 1; m < 16; m <<= 1) s2 += __shfl_xor(s2, m);
    const float rstd = rsqrtf(s2 * (1.0f / 128.0f) + 1e-5f);
    const int c0 = sub * 8;
    const float4 g0 = *(const float4*)(ln2g + c0);
    const float4 g1 = *(const float4*)(ln2g + c0 + 4);
    const float4 bb0 = *(const float4*)(ln2b + c0);
    const float4 bb1 = *(const float4*)(ln2b + c0 + 4);
    float4 r0, r1;
    r0.x = (v[0] - mu) * rstd * g0.x + bb0.x;
    r0.y = (v[1] - mu) * rstd * g0.y + bb0.y;
    r0.z = (v[2] - mu) * rstd * g0.z + bb0.z;
    r0.w = (v[3] - mu) * rstd * g0.w + bb0.w;
    r1.x = (v[4] - mu) * rstd * g1.x + bb1.x;
    r1.y = (v[5] - mu) * rstd * g1.y + bb1.y;
    r1.z = (v[6] - mu) * rstd * g1.z + bb1.z;
    r1.w = (v[7] - mu) * rstd * g1.w + bb1.w;
    float* op = out + ((size_t)row * NN + n) * CC + c0;
    *(float4*)op = r0;
    *(float4*)(op + 4) = r1;
  }
}

// ---------------------------------------------------------------------------
// Fallback: round-1 fp32 kernel if ws too small for packing (never expected).
// ---------------------------------------------------------------------------
__global__ __launch_bounds__(512, 4) void fused_retention_block(
    const float* __restrict__ x,
    const float* __restrict__ wq, const float* __restrict__ bq,
    const float* __restrict__ wk, const float* __restrict__ bk,
    const float* __restrict__ wv, const float* __restrict__ bv,
    const float* __restrict__ ln1g, const float* __restrict__ ln1b,
    const float* __restrict__ w1, const float* __restrict__ b1,
    const float* __restrict__ w2, const float* __restrict__ b2,
    const float* __restrict__ ln2g, const float* __restrict__ ln2b,
    float* __restrict__ out)
{
  const int n = blockIdx.x;
  const int t = threadIdx.x;
  __shared__ float SM[3 * BS * QS];
  float* Qs = SM;
  float* Ks = SM + BS * QS;
  float* Vs = SM + 2 * BS * QS;
  {
    const int o4 = t & 31;
    const int sp = t >> 5;
    const float* xr0 = x + ((size_t)(2 * sp) * NN + n) * CC;
    const float* xr1 = xr0 + (size_t)NN * CC;
    for (int m = 0; m < 3; ++m) {
      const float* W  = (m == 0) ? wq : (m == 1) ? wk : wv;
      const float* bb = (m == 0) ? bq : (m == 1) ? bk : bv;
      float* O = SM + m * BS * QS;
      float b4[4];
      *(float4*)b4 = *(const float4*)(bb + o4 * 4);
      float a0[4] = {b4[0], b4[1], b4[2], b4[3]};
      float a1[4] = {b4[0], b4[1], b4[2], b4[3]};
      for (int c4 = 0; c4 < 32; ++c4) {
        float xa4[4], xb4[4];
        *(float4*)xa4 = *(const float4*)(xr0 + c4 * 4);
        *(float4*)xb4 = *(const float4*)(xr1 + c4 * 4);
        const float* wp = W + (c4 * 4) * CC + o4 * 4;
        #pragma unroll
        for (int j = 0; j < 4; ++j) {
          float w4[4];
          *(float4*)w4 = *(const float4*)(wp + j * CC);
          #pragma unroll
          for (int e = 0; e < 4; ++e) { a0[e] += xa4[j] * w4[e]; a1[e] += xb4[j] * w4[e]; }
        }
      }
      float* q0 = O + (2 * sp) * QS + o4 * 4;
      float* q1 = O + (2 * sp + 1) * QS + o4 * 4;
      #pragma unroll
      for (int e = 0; e < 4; ++e) { q0[e] = a0[e]; q1[e] = a1[e]; }
    }
  }
  __syncthreads();
  {
    const int tt = t & 255;
    const int s = tt >> 3;
    const int h = tt & 7;
    float* row = ((t < 256) ? Qs : Ks) + s * QS + h * DD;
    float v[DD];
    #pragma unroll
    for (int d = 0; d < DD; ++d) v[d] = row[d];
    #pragma unroll
    for (int d = 0; d < DD; ++d) {
      const int j = d >> 1;
      const float a = exp2f(-1.89824462565f * (float)j);
      const float ang = (float)s * a;
      const float sn = sinf(ang);
      const float cs = cosf(ang);
      const float rot = (d < 8) ? -v[2 * d + 1] : v[2 * (d - 8)];
      row[d] = v[d] * cs + rot * sn;
    }
  }
  __syncthreads();
  if (t < 256) {
    const int h = t >> 5;
    const int qi = t & 31;
    const float dec = log1pf(-exp2f(-(1.0f + 0.375f * (float)h)));
    float q[DD];
    const float* Qr = Qs + qi * QS + h * DD;
    #pragma unroll
    for (int d = 0; d < DD; ++d) q[d] = Qr[d];
    float sc[BS];
    float mx = -3.0e38f;
    #pragma unroll
    for (int jj = 0; jj < BS; ++jj) {
      const float* Kr = Ks + jj * QS + h * DD;
      float acc = fabsf((float)(qi - jj)) * dec;
      #pragma unroll
      for (int d = 0; d < DD; ++d) acc += q[d] * Kr[d];
      sc[jj] = acc;
      mx = fmaxf(mx, acc);
    }
    float sum = 0.0f;
    #pragma unroll
    for (int jj = 0; jj < BS; ++jj) { const float p = __expf(sc[jj] - mx); sc[jj] = p; sum += p; }
    const float inv = 1.0f / sum;
    float o[DD];
    #pragma unroll
    for (int d = 0; d < DD; ++d) o[d] = 0.0f;
    #pragma unroll
    for (int jj = 0; jj < BS; ++jj) {
      const float p = sc[jj] * inv;
      const float* Vr = Vs + jj * QS + h * DD;
      #pragma unroll
      for (int d = 0; d < DD; ++d) o[d] += p * Vr[d];
    }
    float* Od = Qs + qi * QS + h * DD;
    #pragma unroll
    for (int d = 0; d < DD; ++d) Od[d] = o[d];
  }
  __syncthreads();
  {
    const int row = t >> 4;
    const int sub = t & 15;
    float* Orow = Qs + row * QS + sub * 8;
    const float* xrow = x + ((size_t)row * NN + n) * CC + sub * 8;
    float v[8];
    #pragma unroll
    for (int i = 0; i < 8; ++i) v[i] = Orow[i] + xrow[i];
    float sum = 0.0f;
    #pragma unroll
    for (int i = 0; i < 8; ++i) sum += v[i];
    #pragma unroll
    for (int m = 1; m < 16; m <<= 1) sum += __shfl_xor(sum, m);
    const float mu = sum * (1.0f / 128.0f);
    float s2 = 0.0f;
    #pragma unroll
    for (int i = 0; i < 8; ++i) { const float d = v[i] - mu; s2 += d * d; }
    #pragma unroll
    for (int m = 1; m < 16; m <<= 1) s2 += __shfl_xor(s2, m);
    const float rstd = rsqrtf(s2 * (1.0f / 128.0f) + 1e-5f);
    #pragma unroll
    for (int i = 0; i < 8; ++i) {
      const int c = sub * 8 + i;
      Orow[i] = (v[i] - mu) * rstd * ln1g[c] + ln1b[c];
    }
  }
  __syncthreads();
  float* Hb = Ks;
  const int f4  = t & 127;
  const int sb4 = (t >> 7) * 4;
  const int o4f = t & 31;
  const int sF  = t >> 5;
  for (int p = 0; p < 2; ++p) {
    {
      float acc[4][4];
      float b14[4];
      *(float4*)b14 = *(const float4*)(b1 + f4 * 4);
      #pragma unroll
      for (int i = 0; i < 4; ++i)
        #pragma unroll
        for (int e = 0; e < 4; ++e) acc[i][e] = b14[e];
      const float* O1b = Qs + (p * 16 + sb4) * QS;
      for (int c = 0; c < CC; ++c) {
        float w4[4];
        *(float4*)w4 = *(const float4*)(w1 + c * FF + f4 * 4);
        #pragma unroll
        for (int i = 0; i < 4; ++i) {
          const float xv = O1b[i * QS + c];
          #pragma unroll
          for (int e = 0; e < 4; ++e) acc[i][e] += xv * w4[e];
        }
      }
      #pragma unroll
      for (int i = 0; i < 4; ++i) {
        float4 r;
        r.x = fmaxf(acc[i][0], 0.0f); r.y = fmaxf(acc[i][1], 0.0f);
        r.z = fmaxf(acc[i][2], 0.0f); r.w = fmaxf(acc[i][3], 0.0f);
        *(float4*)(Hb + (sb4 + i) * FF + f4 * 4) = r;
      }
    }
    __syncthreads();
    {
      const int s = p * 16 + sF;
      float acc[4];
      *(float4*)acc = *(const float4*)(b2 + o4f * 4);
      const float* hrow = Hb + sF * FF;
      for (int k = 0; k < FF; ++k) {
        const float hv = hrow[k];
        float w4[4];
        *(float4*)w4 = *(const float4*)(w2 + k * CC + o4f * 4);
        #pragma unroll
        for (int e = 0; e < 4; ++e) acc[e] += hv * w4[e];
      }
      const float* res = Qs + s * QS + o4f * 4;
      #pragma unroll
      for (int e = 0; e < 4; ++e) acc[e] += res[e];
      float sum = acc[0] + acc[1] + acc[2] + acc[3];
      #pragma unroll
      for (int m = 1; m < 32; m <<= 1) sum += __shfl_xor(sum, m);
      const float mu = sum * (1.0f / 128.0f);
      float s2 = 0.0f;
      #pragma unroll
      for (int e = 0; e < 4; ++e) { const float d = acc[e] - mu; s2 += d * d; }
      #pragma unroll
      for (int m = 1; m < 32; m <<= 1) s2 += __shfl_xor(s2, m);
      const float rstd = rsqrtf(s2 * (1.0f / 128.0f) + 1e-5f);
      float4 r;
      const int c0 = o4f * 4;
      r.x = (acc[0] - mu) * rstd * ln2g[c0 + 0] + ln2b[c0 + 0];
      r.y = (acc[1] - mu) * rstd * ln2g[c0 + 1] + ln2b[c0 + 1];
      r.z = (acc[2] - mu) * rstd * ln2g[c0 + 2] + ln2b[c0 + 2];
      r.w = (acc[3] - mu) * rstd * ln2g[c0 + 3] + ln2b[c0 + 3];
      *(float4*)(out + ((size_t)s * NN + n) * CC + c0) = r;
    }
    __syncthreads();
  }
}

extern "C" void kernel_launch(void* const* d_in, const int* in_sizes, int n_in,
                              void* d_out, int out_size, void* d_ws, size_t ws_size,
                              hipStream_t stream) {
  (void)in_sizes; (void)n_in; (void)out_size;
  const float* x    = (const float*)d_in[0];
  const float* wq   = (const float*)d_in[1];
  const float* bq_  = (const float*)d_in[2];
  const float* wk   = (const float*)d_in[3];
  const float* bk_  = (const float*)d_in[4];
  const float* wv   = (const float*)d_in[5];
  const float* bv_  = (const float*)d_in[6];
  const float* ln1g = (const float*)d_in[7];
  const float* ln1b = (const float*)d_in[8];
  const float* w1   = (const float*)d_in[9];
  const float* b1   = (const float*)d_in[10];
  const float* w2   = (const float*)d_in[11];
  const float* b2   = (const float*)d_in[12];
  const float* ln2g = (const float*)d_in[13];
  const float* ln2b = (const float*)d_in[14];
  float* outp = (float*)d_out;

  if (ws_size >= (size_t)364544) {
    unsigned short* wpack = (unsigned short*)d_ws;
    const float2* rott = (const float2*)((const char*)d_ws + 360448);
    pack_weights<<<90, 256, 0, stream>>>(wq, wk, wv, w1, w2, wpack);
    fused_mfma<<<NN, 512, LDS_BYTES, stream>>>(
        x, bq_, bk_, bv_, ln1g, ln1b, b1, b2, ln2g, ln2b, wpack, rott, outp);
  } else {
    fused_retention_block<<<NN, 512, 0, stream>>>(
        x, wq, bq_, wk, bk_, wv, bv_, ln1g, ln1b,
        w1, b1, w2, b2, ln2g, ln2b, outp);
  }
}

// Round 13
// 216.012 us; speedup vs baseline: 1.4715x; 1.4715x over previous
//
#include <hip/hip_runtime.h>
#include <hip/hip_bf16.h>

// Fused retention block, round 13 = r11 champion (200us) + setprio + packed
// V^T writes + vectorized LN2 param loads. No structural changes vs r11.
// grid = 8192 (one block per n), 512 threads = 8 waves (wave w = head w in attn).
// d_ws: [0,98304) QKV bf16 frags | [98304,229376) w1 bf16 frags |
//       [229376,294912) w2 FP8 frags | [360448,364544) rot table f32x2[32][16].
// LDS pool 39424 B. Lifetime map (bytes):
//   XB  [0,8704)      bf16[32][136] x tile         (dead after LN1 reads)
//   QB  [8704,17408)  bf16[32][136] rot Q          (dead after attn frag preload)
//   KB  [17408,26112) bf16[32][136] rot K          (dead after attn frag preload)
//   VT  [26112,35328) bf16 8x[16][36] V^T          (dead after attn frag preload)
//   TAB [35328,39424) f32x2[512] rot table         (dead after QKV epilogue)
//   P   [8704,27136)  bf16 8x[32][36] over QB/KB/VT0, after mid-attn barrier
//   OO  [27136,35840) bf16[32][136]: attn-out -> LN1-out(in place) -> O2(in place)
//   H   [0,16640)     fp8[32][520] over XB/QB (written in FFN1, after LN1 barrier)
// Barriers: stage | QKV | mid-attn | attn | LN1 | FFN1 | FFN2 = 7

#define NN 8192
#define BS 32
#define CC 128
#define HH 8
#define DD 16
#define FF 512
#define QS 129   // fp32 fallback stride

typedef __attribute__((ext_vector_type(8))) short bf16x8;
typedef __attribute__((ext_vector_type(4))) float f32x4;
typedef __attribute__((ext_vector_type(4))) unsigned int u32x4;
typedef __attribute__((ext_vector_type(2))) unsigned int u32x2;

#define XB_H 0
#define QB_H 4352
#define KB_H 8704
#define VT_H 13056
#define TAB_F 8832
#define P_H 4352
#define P_HEAD 1152
#define P_STR 36
#define OO_H 13568
#define H_STR 520
#define W2FP8_OFF 229376
#define LDS_BYTES 39424

__device__ inline unsigned short f2bf(float f) {
  return __builtin_bit_cast(unsigned short, __float2bfloat16(f));
}
__device__ inline unsigned pk2bf(float lo, float hi) {
  return (unsigned)f2bf(lo) | ((unsigned)f2bf(hi) << 16);
}
__device__ inline float bf2f(unsigned short h) {
  unsigned u = ((unsigned)h) << 16;
  return __builtin_bit_cast(float, u);
}

// f32 -> fp8 e4m3fn (OCP), software fallback
__device__ inline unsigned char f2fp8_sw(float x) {
  unsigned u = __builtin_bit_cast(unsigned, x);
  unsigned sign = (u >> 31) << 7;
  float ax = fabsf(x);
  if (!(ax >= 0.015625f)) {
    int q = (int)(ax * 512.0f + 0.5f);
    if (q > 7) return (unsigned char)(sign | 8);
    return (unsigned char)(sign | q);
  }
  if (ax > 448.0f) ax = 448.0f;
  unsigned au = __builtin_bit_cast(unsigned, ax);
  int exp = (int)((au >> 23) & 0xff) - 127;
  unsigned m3 = ((au & 0x7fffff) + 0x80000) >> 20;
  if (m3 >= 8) { m3 = 0; exp += 1; }
  if (exp > 8) return (unsigned char)(sign | 0x7e);
  return (unsigned char)(sign | ((unsigned)(exp + 7) << 3) | m3);
}
__device__ inline unsigned char f2fp8(float x) {
#if defined(__has_builtin) && __has_builtin(__builtin_amdgcn_cvt_pk_fp8_f32)
  return (unsigned char)(__builtin_amdgcn_cvt_pk_fp8_f32(x, x, 0, false) & 0xff);
#else
  return f2fp8_sw(x);
#endif
}
__device__ inline unsigned pack4fp8(float a, float b, float c, float d) {
#if defined(__has_builtin) && __has_builtin(__builtin_amdgcn_cvt_pk_fp8_f32)
  int r = __builtin_amdgcn_cvt_pk_fp8_f32(a, b, 0, false);
  r = __builtin_amdgcn_cvt_pk_fp8_f32(c, d, r, true);
  return (unsigned)r;
#else
  return (unsigned)f2fp8_sw(a) | ((unsigned)f2fp8_sw(b) << 8) |
         ((unsigned)f2fp8_sw(c) << 16) | ((unsigned)f2fp8_sw(d) << 24);
#endif
}

// ---------------------------------------------------------------------------
// Pack kernel (unchanged from r11).
// ---------------------------------------------------------------------------
__global__ void pack_weights(const float* __restrict__ wq, const float* __restrict__ wk,
                             const float* __restrict__ wv, const float* __restrict__ w1,
                             const float* __restrict__ w2, unsigned short* __restrict__ outp)
{
  const int id = blockIdx.x * 256 + threadIdx.x;
  if (id >= 23040) return;
  if (id >= 22528) {
    const int i = id - 22528;
    const int s = i >> 4, d = i & 15;
    const float a = exp2f(-1.89824462565f * (float)(d >> 1));
    const float ang = (float)s * a;
    float2* tab = (float2*)(outp + 180224);
    tab[i] = make_float2(sinf(ang), cosf(ang));
    return;
  }
  const int l = id & 63;
  const int chunk = id >> 6;
  if (chunk >= 224) {
    const int c2 = chunk - 224, ct = c2 >> 4, kk = c2 & 15;
    const int colbase = ct * 16 + (l & 15);
    const int k0 = kk * 32 + (l >> 4) * 8;
    float v[8];
    #pragma unroll
    for (int jj = 0; jj < 8; ++jj) v[jj] = w2[(size_t)(k0 + jj) * CC + colbase];
    u32x2 pw;
    pw[0] = pack4fp8(v[0], v[1], v[2], v[3]);
    pw[1] = pack4fp8(v[4], v[5], v[6], v[7]);
    *(u32x2*)((char*)outp + W2FP8_OFF + ((size_t)c2 * 64 + l) * 8) = pw;
    return;
  }
  const float* W; int ldw, colbase, k0;
  if (chunk < 96) {
    const int ct = chunk >> 2, kk = chunk & 3;
    W = (ct < 8) ? wq : (ct < 16) ? wk : wv;
    ldw = CC; colbase = (ct & 7) * 16 + (l & 15); k0 = kk * 32 + (l >> 4) * 8;
  } else {
    const int c2 = chunk - 96, ct = c2 >> 2, kk = c2 & 3;
    W = w1; ldw = FF; colbase = ct * 16 + (l & 15); k0 = kk * 32 + (l >> 4) * 8;
  }
  unsigned int o[4];
  #pragma unroll
  for (int jj = 0; jj < 4; ++jj)
    o[jj] = pk2bf(W[(size_t)(k0 + 2 * jj) * ldw + colbase],
                  W[(size_t)(k0 + 2 * jj + 1) * ldw + colbase]);
  *(u32x4*)(outp + (size_t)id * 8) = (u32x4){o[0], o[1], o[2], o[3]};
}

__global__ __launch_bounds__(512, 6) void fused_mfma(
    const float* __restrict__ x,
    const float* __restrict__ bq, const float* __restrict__ bk, const float* __restrict__ bv,
    const float* __restrict__ ln1g, const float* __restrict__ ln1b,
    const float* __restrict__ b1, const float* __restrict__ b2,
    const float* __restrict__ ln2g, const float* __restrict__ ln2b,
    const unsigned short* __restrict__ wpack,
    const float2* __restrict__ rott,
    float* __restrict__ out)
{
  extern __shared__ char smem[];
  float* ldsf = (float*)smem;
  unsigned short* ldsh = (unsigned short*)smem;
  const int n = blockIdx.x;
  const int t = threadIdx.x;
  const int w = t >> 6;
  const int l = t & 63;
  const int lr = l & 15;
  const int lg = l >> 4;

  // ---------------- stage X -> bf16 LDS + rot table ------------------------
  {
    const int s = t >> 4, c0 = (t & 15) * 8;
    const float* xp = x + ((size_t)s * NN + n) * CC + c0;
    const float4 v0 = *(const float4*)xp;
    const float4 v1 = *(const float4*)(xp + 4);
    u32x4 pk;
    pk[0] = pk2bf(v0.x, v0.y);
    pk[1] = pk2bf(v0.z, v0.w);
    pk[2] = pk2bf(v1.x, v1.y);
    pk[3] = pk2bf(v1.z, v1.w);
    *(u32x4*)(ldsh + XB_H + s * 136 + c0) = pk;
    ((float2*)(ldsf + TAB_F))[t] = rott[t];
  }
  __syncthreads();

  // ---------------- QKV MFMA + fused rotary epilogue (r11 shape) -----------
  {
    f32x4 acc[2][3];
    #pragma unroll
    for (int c = 0; c < 3; ++c) {
      const int ct = 3 * w + c;
      const int col = (ct & 7) * 16 + lr;
      const float* bb = (ct < 8) ? bq : (ct < 16) ? bk : bv;
      const float b = bb[col];
      acc[0][c] = (f32x4){b, b, b, b};
      acc[1][c] = acc[0][c];
    }
    __builtin_amdgcn_s_setprio(1);
    #pragma unroll
    for (int kk = 0; kk < 4; ++kk) {
      const bf16x8 a0 = *(const bf16x8*)(ldsh + XB_H + lr * 136 + kk * 32 + lg * 8);
      const bf16x8 a1 = *(const bf16x8*)(ldsh + XB_H + (16 + lr) * 136 + kk * 32 + lg * 8);
      #pragma unroll
      for (int c = 0; c < 3; ++c) {
        const int ct = 3 * w + c;
        const bf16x8 b = *(const bf16x8*)(wpack + ((size_t)(ct * 4 + kk) * 64 + l) * 8);
        acc[0][c] = __builtin_amdgcn_mfma_f32_16x16x32_bf16(a0, b, acc[0][c], 0, 0, 0);
        acc[1][c] = __builtin_amdgcn_mfma_f32_16x16x32_bf16(a1, b, acc[1][c], 0, 0, 0);
      }
    }
    __builtin_amdgcn_s_setprio(0);
    float sn[2][4], cs[2][4];
    if (3 * w < 16) {   // wave-uniform: only waves holding Q/K coltiles
      #pragma unroll
      for (int rt = 0; rt < 2; ++rt)
        #pragma unroll
        for (int e = 0; e < 4; ++e) {
          const int row = rt * 16 + lg * 4 + e;
          const float2 tc = ((const float2*)(ldsf + TAB_F))[row * 16 + lr];
          sn[rt][e] = tc.x;
          cs[rt][e] = tc.y;
        }
    }
    const int pd = (lr < 8) ? (2 * lr + 1) : (2 * lr - 16);
    const float sgn = (lr < 8) ? -1.0f : 1.0f;
    const int psrc = (l & 48) | pd;
    #pragma unroll
    for (int c = 0; c < 3; ++c) {
      const int ct = 3 * w + c;
      if (ct < 16) {
        const int dst = (ct < 8) ? QB_H : KB_H;
        const int colbase = (ct & 7) * 16;
        #pragma unroll
        for (int rt = 0; rt < 2; ++rt)
          #pragma unroll
          for (int e = 0; e < 4; ++e) {
            const float v = acc[rt][c][e];
            const float pv = __shfl(v, psrc);
            const float r = v * cs[rt][e] + sgn * pv * sn[rt][e];
            ldsh[dst + (rt * 16 + lg * 4 + e) * 136 + colbase + lr] = f2bf(r);
          }
      } else {
        // V^T: packed 4-short writes (e-contiguous)
        const int hv = ct - 16;
        #pragma unroll
        for (int rt = 0; rt < 2; ++rt) {
          u32x2 pw;
          pw[0] = pk2bf(acc[rt][c][0], acc[rt][c][1]);
          pw[1] = pk2bf(acc[rt][c][2], acc[rt][c][3]);
          *(u32x2*)(ldsh + VT_H + hv * 576 + lr * 36 + rt * 16 + lg * 4) = pw;
        }
      }
    }
  }
  __syncthreads();

  // ---------------- MFMA attention: wave w = head w ------------------------
  {
    const int h16 = w * 16;
    const float dec = log1pf(-exp2f(-(1.0f + 0.375f * (float)w)));
    const bf16x8 z = {};
    bf16x8 Ak[2], Bq[2];
    #pragma unroll
    for (int kt = 0; kt < 2; ++kt)
      Ak[kt] = (lg < 2) ? *(const bf16x8*)(ldsh + KB_H + (kt * 16 + lr) * 136 + h16 + lg * 8) : z;
    #pragma unroll
    for (int qt = 0; qt < 2; ++qt)
      Bq[qt] = (lg < 2) ? *(const bf16x8*)(ldsh + QB_H + (qt * 16 + lr) * 136 + h16 + lg * 8) : z;
    const bf16x8 Bv = *(const bf16x8*)(ldsh + VT_H + w * 576 + lr * 36 + lg * 8);
    __syncthreads();   // frags in regs; QB/KB/VT now reusable as P; OO writable

    f32x4 accs[2][2];
    __builtin_amdgcn_s_setprio(1);
    #pragma unroll
    for (int kt = 0; kt < 2; ++kt)
      #pragma unroll
      for (int qt = 0; qt < 2; ++qt) {
        #pragma unroll
        for (int e = 0; e < 4; ++e) {
          const int q = qt * 16 + lr;
          const int k = kt * 16 + lg * 4 + e;
          accs[kt][qt][e] = fabsf((float)(q - k)) * dec;
        }
        accs[kt][qt] = __builtin_amdgcn_mfma_f32_16x16x32_bf16(Ak[kt], Bq[qt], accs[kt][qt], 0, 0, 0);
      }
    __builtin_amdgcn_s_setprio(0);
    unsigned short* Pl = ldsh + P_H + w * P_HEAD;
    #pragma unroll
    for (int qt = 0; qt < 2; ++qt) {
      float mx = accs[0][qt][0];
      #pragma unroll
      for (int kt = 0; kt < 2; ++kt)
        #pragma unroll
        for (int e = 0; e < 4; ++e) mx = fmaxf(mx, accs[kt][qt][e]);
      mx = fmaxf(mx, __shfl_xor(mx, 16));
      mx = fmaxf(mx, __shfl_xor(mx, 32));
      float p[2][4];
      float sm = 0.0f;
      #pragma unroll
      for (int kt = 0; kt < 2; ++kt)
        #pragma unroll
        for (int e = 0; e < 4; ++e) { p[kt][e] = __expf(accs[kt][qt][e] - mx); sm += p[kt][e]; }
      sm += __shfl_xor(sm, 16);
      sm += __shfl_xor(sm, 32);
      const float inv = 1.0f / sm;
      #pragma unroll
      for (int kt = 0; kt < 2; ++kt) {
        u32x2 pw;
        pw[0] = pk2bf(p[kt][0] * inv, p[kt][1] * inv);
        pw[1] = pk2bf(p[kt][2] * inv, p[kt][3] * inv);
        *(u32x2*)(Pl + (qt * 16 + lr) * P_STR + kt * 16 + lg * 4) = pw;
      }
    }
    // PV: Bv preloaded; attn-out -> OO region
    __builtin_amdgcn_s_setprio(1);
    #pragma unroll
    for (int qt = 0; qt < 2; ++qt) {
      const bf16x8 Ap = *(const bf16x8*)(Pl + (qt * 16 + lr) * P_STR + lg * 8);
      f32x4 z4 = {0.0f, 0.0f, 0.0f, 0.0f};
      const f32x4 o = __builtin_amdgcn_mfma_f32_16x16x32_bf16(Ap, Bv, z4, 0, 0, 0);
      #pragma unroll
      for (int e = 0; e < 4; ++e)
        ldsh[OO_H + (qt * 16 + lg * 4 + e) * 136 + h16 + lr] = f2bf(o[e]);
    }
    __builtin_amdgcn_s_setprio(0);
  }
  __syncthreads();

  // ---------------- LN1(attn_out + x) -> bf16, in place over OO ------------
  {
    const int row = t >> 4, sub = t & 15;
    const unsigned short* Or = ldsh + OO_H + row * 136 + sub * 8;
    const unsigned short* Xr = ldsh + XB_H + row * 136 + sub * 8;
    float v[8];
    #pragma unroll
    for (int i = 0; i < 8; ++i) v[i] = bf2f(Or[i]) + bf2f(Xr[i]);
    float sum = 0.0f;
    #pragma unroll
    for (int i = 0; i < 8; ++i) sum += v[i];
    #pragma unroll
    for (int m = 1; m < 16; m <<= 1) sum += __shfl_xor(sum, m);
    const float mu = sum * (1.0f / 128.0f);
    float s2 = 0.0f;
    #pragma unroll
    for (int i = 0; i < 8; ++i) { const float d = v[i] - mu; s2 += d * d; }
    #pragma unroll
    for (int m = 1; m < 16; m <<= 1) s2 += __shfl_xor(s2, m);
    const float rstd = rsqrtf(s2 * (1.0f / 128.0f) + 1e-5f);
    u32x4 pk;
    #pragma unroll
    for (int i = 0; i < 4; ++i) {
      const int c = sub * 8 + 2 * i;
      pk[i] = pk2bf((v[2 * i] - mu) * rstd * ln1g[c] + ln1b[c],
                    (v[2 * i + 1] - mu) * rstd * ln1g[c + 1] + ln1b[c + 1]);
    }
    *(u32x4*)(ldsh + OO_H + row * 136 + sub * 8) = pk;   // same addrs this thread read
  }
  __syncthreads();

  // ---------------- FFN1: H fp8[32][520] = relu(O1 @ w1 + b1) --------------
  {
    f32x4 acc1[2][4];
    #pragma unroll
    for (int c = 0; c < 4; ++c) {
      const float b = b1[(4 * w + c) * 16 + lr];
      acc1[0][c] = (f32x4){b, b, b, b};
      acc1[1][c] = acc1[0][c];
    }
    __builtin_amdgcn_s_setprio(1);
    #pragma unroll
    for (int kk = 0; kk < 4; ++kk) {
      const bf16x8 a0 = *(const bf16x8*)(ldsh + OO_H + lr * 136 + kk * 32 + lg * 8);
      const bf16x8 a1 = *(const bf16x8*)(ldsh + OO_H + (16 + lr) * 136 + kk * 32 + lg * 8);
      #pragma unroll
      for (int c = 0; c < 4; ++c) {
        const int chunk = 96 + (4 * w + c) * 4 + kk;
        const bf16x8 b = *(const bf16x8*)(wpack + ((size_t)chunk * 64 + l) * 8);
        acc1[0][c] = __builtin_amdgcn_mfma_f32_16x16x32_bf16(a0, b, acc1[0][c], 0, 0, 0);
        acc1[1][c] = __builtin_amdgcn_mfma_f32_16x16x32_bf16(a1, b, acc1[1][c], 0, 0, 0);
      }
    }
    __builtin_amdgcn_s_setprio(0);
    char* Hb = smem;   // H over dead XB/QB, [0,16640)
    #pragma unroll
    for (int p = 0; p < 2; ++p)
      #pragma unroll
      for (int c = 0; c < 4; ++c) {
        const int col = (4 * w + c) * 16 + lr;
        #pragma unroll
        for (int e = 0; e < 4; ++e) {
          const int row = p * 16 + lg * 4 + e;
          Hb[row * H_STR + col] = (char)f2fp8(fmaxf(acc1[p][c][e], 0.0f));
        }
      }
  }
  __syncthreads();

  // ---------------- FFN2 (fp8): O2 = H @ w2 + b2 + O1, in place over OO ----
  {
    const int col = w * 16 + lr;
    const float b = b2[col];
    f32x4 acc2[2];
    acc2[0] = (f32x4){b, b, b, b};
    acc2[1] = acc2[0];
    const char* Hb = smem;
    const char* W2 = (const char*)wpack + W2FP8_OFF;
    __builtin_amdgcn_s_setprio(1);
    #pragma unroll
    for (int kk = 0; kk < 16; ++kk) {
      const long a0 = *(const long*)(Hb + lr * H_STR + kk * 32 + lg * 8);
      const long a1 = *(const long*)(Hb + (16 + lr) * H_STR + kk * 32 + lg * 8);
      const long bb = *(const long*)(W2 + ((size_t)(w * 16 + kk) * 64 + l) * 8);
      acc2[0] = __builtin_amdgcn_mfma_f32_16x16x32_fp8_fp8(a0, bb, acc2[0], 0, 0, 0);
      acc2[1] = __builtin_amdgcn_mfma_f32_16x16x32_fp8_fp8(a1, bb, acc2[1], 0, 0, 0);
    }
    __builtin_amdgcn_s_setprio(0);
    #pragma unroll
    for (int p = 0; p < 2; ++p)
      #pragma unroll
      for (int e = 0; e < 4; ++e) {
        const int srow = p * 16 + lg * 4 + e;
        const int idx = OO_H + srow * 136 + col;
        const float res = bf2f(ldsh[idx]);                 // same-thread RAW, safe
        ldsh[idx] = f2bf(acc2[p][e] + res);
      }
  }
  __syncthreads();

  // ---------------- LN2 (32 rows at once) + transposed store ---------------
  {
    const int row = t >> 4, sub = t & 15;
    const unsigned short* Or = ldsh + OO_H + row * 136 + sub * 8;
    float v[8];
    #pragma unroll
    for (int i = 0; i < 8; ++i) v[i] = bf2f(Or[i]);
    float sum = 0.0f;
    #pragma unroll
    for (int i = 0; i < 8; ++i) sum += v[i];
    #pragma unroll
    for (int m = 1; m < 16; m <<= 1) sum += __shfl_xor(sum, m);
    const float mu = sum * (1.0f / 128.0f);
    float s2 = 0.0f;
    #pragma unroll
    for (int i = 0; i < 8; ++i) { const float d = v[i] - mu; s2 += d * d; }
    #pragma unroll
    for (int m = 1; m < 16; m <<= 1) s2 += __shfl_xor(s2, m);
    const float rstd = rsqrtf(s2 * (1.0f / 128.0f) + 1e-5f);
    const int c0 = sub * 8;
    const float4 g0 = *(const float4*)(ln2g + c0);
    const float4 g1 = *(const float4*)(ln2g + c0 + 4);
    const float4 bb0 = *(const float4*)(ln2b + c0);
    const float4 bb1 = *(const float4*)(ln2b + c0 + 4);
    float4 r0, r1;
    r0.x = (v[0] - mu) * rstd * g0.x + bb0.x;
    r0.y = (v[1] - mu) * rstd * g0.y + bb0.y;
    r0.z = (v[2] - mu) * rstd * g0.z + bb0.z;
    r0.w = (v[3] - mu) * rstd * g0.w + bb0.w;
    r1.x = (v[4] - mu) * rstd * g1.x + bb1.x;
    r1.y = (v[5] - mu) * rstd * g1.y + bb1.y;
    r1.z = (v[6] - mu) * rstd * g1.z + bb1.z;
    r1.w = (v[7] - mu) * rstd * g1.w + bb1.w;
    float* op = out + ((size_t)row * NN + n) * CC + c0;
    *(float4*)op = r0;
    *(float4*)(op + 4) = r1;
  }
}

// ---------------------------------------------------------------------------
// Fallback: round-1 fp32 kernel if ws too small for packing (never expected).
// ---------------------------------------------------------------------------
__global__ __launch_bounds__(512, 4) void fused_retention_block(
    const float* __restrict__ x,
    const float* __restrict__ wq, const float* __restrict__ bq,
    const float* __restrict__ wk, const float* __restrict__ bk,
    const float* __restrict__ wv, const float* __restrict__ bv,
    const float* __restrict__ ln1g, const float* __restrict__ ln1b,
    const float* __restrict__ w1, const float* __restrict__ b1,
    const float* __restrict__ w2, const float* __restrict__ b2,
    const float* __restrict__ ln2g, const float* __restrict__ ln2b,
    float* __restrict__ out)
{
  const int n = blockIdx.x;
  const int t = threadIdx.x;
  __shared__ float SM[3 * BS * QS];
  float* Qs = SM;
  float* Ks = SM + BS * QS;
  float* Vs = SM + 2 * BS * QS;
  {
    const int o4 = t & 31;
    const int sp = t >> 5;
    const float* xr0 = x + ((size_t)(2 * sp) * NN + n) * CC;
    const float* xr1 = xr0 + (size_t)NN * CC;
    for (int m = 0; m < 3; ++m) {
      const float* W  = (m == 0) ? wq : (m == 1) ? wk : wv;
      const float* bb = (m == 0) ? bq : (m == 1) ? bk : bv;
      float* O = SM + m * BS * QS;
      float b4[4];
      *(float4*)b4 = *(const float4*)(bb + o4 * 4);
      float a0[4] = {b4[0], b4[1], b4[2], b4[3]};
      float a1[4] = {b4[0], b4[1], b4[2], b4[3]};
      for (int c4 = 0; c4 < 32; ++c4) {
        float xa4[4], xb4[4];
        *(float4*)xa4 = *(const float4*)(xr0 + c4 * 4);
        *(float4*)xb4 = *(const float4*)(xr1 + c4 * 4);
        const float* wp = W + (c4 * 4) * CC + o4 * 4;
        #pragma unroll
        for (int j = 0; j < 4; ++j) {
          float w4[4];
          *(float4*)w4 = *(const float4*)(wp + j * CC);
          #pragma unroll
          for (int e = 0; e < 4; ++e) { a0[e] += xa4[j] * w4[e]; a1[e] += xb4[j] * w4[e]; }
        }
      }
      float* q0 = O + (2 * sp) * QS + o4 * 4;
      float* q1 = O + (2 * sp + 1) * QS + o4 * 4;
      #pragma unroll
      for (int e = 0; e < 4; ++e) { q0[e] = a0[e]; q1[e] = a1[e]; }
    }
  }
  __syncthreads();
  {
    const int tt = t & 255;
    const int s = tt >> 3;
    const int h = tt & 7;
    float* row = ((t < 256) ? Qs : Ks) + s * QS + h * DD;
    float v[DD];
    #pragma unroll
    for (int d = 0; d < DD; ++d) v[d] = row[d];
    #pragma unroll
    for (int d = 0; d < DD; ++d) {
      const int j = d >> 1;
      const float a = exp2f(-1.89824462565f * (float)j);
      const float ang = (float)s * a;
      const float sn = sinf(ang);
      const float cs = cosf(ang);
      const float rot = (d < 8) ? -v[2 * d + 1] : v[2 * (d - 8)];
      row[d] = v[d] * cs + rot * sn;
    }
  }
  __syncthreads();
  if (t < 256) {
    const int h = t >> 5;
    const int qi = t & 31;
    const float dec = log1pf(-exp2f(-(1.0f + 0.375f * (float)h)));
    float q[DD];
    const float* Qr = Qs + qi * QS + h * DD;
    #pragma unroll
    for (int d = 0; d < DD; ++d) q[d] = Qr[d];
    float sc[BS];
    float mx = -3.0e38f;
    #pragma unroll
    for (int jj = 0; jj < BS; ++jj) {
      const float* Kr = Ks + jj * QS + h * DD;
      float acc = fabsf((float)(qi - jj)) * dec;
      #pragma unroll
      for (int d = 0; d < DD; ++d) acc += q[d] * Kr[d];
      sc[jj] = acc;
      mx = fmaxf(mx, acc);
    }
    float sum = 0.0f;
    #pragma unroll
    for (int jj = 0; jj < BS; ++jj) { const float p = __expf(sc[jj] - mx); sc[jj] = p; sum += p; }
    const float inv = 1.0f / sum;
    float o[DD];
    #pragma unroll
    for (int d = 0; d < DD; ++d) o[d] = 0.0f;
    #pragma unroll
    for (int jj = 0; jj < BS; ++jj) {
      const float p = sc[jj] * inv;
      const float* Vr = Vs + jj * QS + h * DD;
      #pragma unroll
      for (int d = 0; d < DD; ++d) o[d] += p * Vr[d];
    }
    float* Od = Qs + qi * QS + h * DD;
    #pragma unroll
    for (int d = 0; d < DD; ++d) Od[d] = o[d];
  }
  __syncthreads();
  {
    const int row = t >> 4;
    const int sub = t & 15;
    float* Orow = Qs + row * QS + sub * 8;
    const float* xrow = x + ((size_t)row * NN + n) * CC + sub * 8;
    float v[8];
    #pragma unroll
    for (int i = 0; i < 8; ++i) v[i] = Orow[i] + xrow[i];
    float sum = 0.0f;
    #pragma unroll
    for (int i = 0; i < 8; ++i) sum += v[i];
    #pragma unroll
    for (int m = 1; m < 16; m <<= 1) sum += __shfl_xor(sum, m);
    const float mu = sum * (1.0f / 128.0f);
    float s2 = 0.0f;
    #pragma unroll
    for (int i = 0; i < 8; ++i) { const float d = v[i] - mu; s2 += d * d; }
    #pragma unroll
    for (int m = 1; m < 16; m <<= 1) s2 += __shfl_xor(s2, m);
    const float rstd = rsqrtf(s2 * (1.0f / 128.0f) + 1e-5f);
    #pragma unroll
    for (int i = 0; i < 8; ++i) {
      const int c = sub * 8 + i;
      Orow[i] = (v[i] - mu) * rstd * ln1g[c] + ln1b[c];
    }
  }
  __syncthreads();
  float* Hb = Ks;
  const int f4  = t & 127;
  const int sb4 = (t >> 7) * 4;
  const int o4f = t & 31;
  const int sF  = t >> 5;
  for (int p = 0; p < 2; ++p) {
    {
      float acc[4][4];
      float b14[4];
      *(float4*)b14 = *(const float4*)(b1 + f4 * 4);
      #pragma unroll
      for (int i = 0; i < 4; ++i)
        #pragma unroll
        for (int e = 0; e < 4; ++e) acc[i][e] = b14[e];
      const float* O1b = Qs + (p * 16 + sb4) * QS;
      for (int c = 0; c < CC; ++c) {
        float w4[4];
        *(float4*)w4 = *(const float4*)(w1 + c * FF + f4 * 4);
        #pragma unroll
        for (int i = 0; i < 4; ++i) {
          const float xv = O1b[i * QS + c];
          #pragma unroll
          for (int e = 0; e < 4; ++e) acc[i][e] += xv * w4[e];
        }
      }
      #pragma unroll
      for (int i = 0; i < 4; ++i) {
        float4 r;
        r.x = fmaxf(acc[i][0], 0.0f); r.y = fmaxf(acc[i][1], 0.0f);
        r.z = fmaxf(acc[i][2], 0.0f); r.w = fmaxf(acc[i][3], 0.0f);
        *(float4*)(Hb + (sb4 + i) * FF + f4 * 4) = r;
      }
    }
    __syncthreads();
    {
      const int s = p * 16 + sF;
      float acc[4];
      *(float4*)acc = *(const float4*)(b2 + o4f * 4);
      const float* hrow = Hb + sF * FF;
      for (int k = 0; k < FF; ++k) {
        const float hv = hrow[k];
        float w4[4];
        *(float4*)w4 = *(const float4*)(w2 + k * CC + o4f * 4);
        #pragma unroll
        for (int e = 0; e < 4; ++e) acc[e] += hv * w4[e];
      }
      const float* res = Qs + s * QS + o4f * 4;
      #pragma unroll
      for (int e = 0; e < 4; ++e) acc[e] += res[e];
      float sum = acc[0] + acc[1] + acc[2] + acc[3];
      #pragma unroll
      for (int m = 1; m < 32; m <<= 1) sum += __shfl_xor(sum, m);
      const float mu = sum * (1.0f / 128.0f);
      float s2 = 0.0f;
      #pragma unroll
      for (int e = 0; e < 4; ++e) { const float d = acc[e] - mu; s2 += d * d; }
      #pragma unroll
      for (int m = 1; m < 32; m <<= 1) s2 += __shfl_xor(s2, m);
      const float rstd = rsqrtf(s2 * (1.0f / 128.0f) + 1e-5f);
      float4 r;
      const int c0 = o4f * 4;
      r.x = (acc[0] - mu) * rstd * ln2g[c0 + 0] + ln2b[c0 + 0];
      r.y = (acc[1] - mu) * rstd * ln2g[c0 + 1] + ln2b[c0 + 1];
      r.z = (acc[2] - mu) * rstd * ln2g[c0 + 2] + ln2b[c0 + 2];
      r.w = (acc[3] - mu) * rstd * ln2g[c0 + 3] + ln2b[c0 + 3];
      *(float4*)(out + ((size_t)s * NN + n) * CC + c0) = r;
    }
    __syncthreads();
  }
}

extern "C" void kernel_launch(void* const* d_in, const int* in_sizes, int n_in,
                              void* d_out, int out_size, void* d_ws, size_t ws_size,
                              hipStream_t stream) {
  (void)in_sizes; (void)n_in; (void)out_size;
  const float* x    = (const float*)d_in[0];
  const float* wq   = (const float*)d_in[1];
  const float* bq_  = (const float*)d_in[2];
  const float* wk   = (const float*)d_in[3];
  const float* bk_  = (const float*)d_in[4];
  const float* wv   = (const float*)d_in[5];
  const float* bv_  = (const float*)d_in[6];
  const float* ln1g = (const float*)d_in[7];
  const float* ln1b = (const float*)d_in[8];
  const float* w1   = (const float*)d_in[9];
  const float* b1   = (const float*)d_in[10];
  const float* w2   = (const float*)d_in[11];
  const float* b2   = (const float*)d_in[12];
  const float* ln2g = (const float*)d_in[13];
  const float* ln2b = (const float*)d_in[14];
  float* outp = (float*)d_out;

  if (ws_size >= (size_t)364544) {
    unsigned short* wpack = (unsigned short*)d_ws;
    const float2* rott = (const float2*)((const char*)d_ws + 360448);
    pack_weights<<<90, 256, 0, stream>>>(wq, wk, wv, w1, w2, wpack);
    fused_mfma<<<NN, 512, LDS_BYTES, stream>>>(
        x, bq_, bk_, bv_, ln1g, ln1b, b1, b2, ln2g, ln2b, wpack, rott, outp);
  } else {
    fused_retention_block<<<NN, 512, 0, stream>>>(
        x, wq, bq_, wk, bk_, wv, bv_, ln1g, ln1b,
        w1, b1, w2, b2, ln2g, ln2b, outp);
  }
}

// Round 14
// 198.241 us; speedup vs baseline: 1.6034x; 1.0896x over previous
//
#include <hip/hip_runtime.h>
#include <hip/hip_bf16.h>

// Fused retention block, round 14 = r11 champion, byte-identical revert.
// (r12 AGPR-split: -118us spill; r13 setprio/vec-graft: -16us spill. Both falsified.)
// grid = 8192 (one block per n), 512 threads = 8 waves (wave w = head w in attn).
// d_ws: [0,98304) QKV bf16 frags | [98304,229376) w1 bf16 frags |
//       [229376,294912) w2 FP8 frags | [360448,364544) rot table f32x2[32][16].
// LDS pool 39424 B. Lifetime map (bytes):
//   XB  [0,8704)      bf16[32][136] x tile         (dead after LN1 reads)
//   QB  [8704,17408)  bf16[32][136] rot Q          (dead after attn frag preload)
//   KB  [17408,26112) bf16[32][136] rot K          (dead after attn frag preload)
//   VT  [26112,35328) bf16 8x[16][36] V^T          (dead after attn frag preload)
//   TAB [35328,39424) f32x2[512] rot table         (dead after QKV epilogue)
//   P   [8704,27136)  bf16 8x[32][36] over QB/KB/VT0, after mid-attn barrier
//   OO  [27136,35840) bf16[32][136]: attn-out -> LN1-out(in place) -> O2(in place)
//   H   [0,16640)     fp8[32][520] over XB/QB (written in FFN1, after LN1 barrier)
// Barriers: stage | QKV | mid-attn | attn | LN1 | FFN1 | FFN2 = 7

#define NN 8192
#define BS 32
#define CC 128
#define HH 8
#define DD 16
#define FF 512
#define QS 129   // fp32 fallback stride

typedef __attribute__((ext_vector_type(8))) short bf16x8;
typedef __attribute__((ext_vector_type(4))) float f32x4;
typedef __attribute__((ext_vector_type(4))) unsigned int u32x4;
typedef __attribute__((ext_vector_type(2))) unsigned int u32x2;

#define XB_H 0
#define QB_H 4352
#define KB_H 8704
#define VT_H 13056
#define TAB_F 8832
#define P_H 4352
#define P_HEAD 1152
#define P_STR 36
#define OO_H 13568
#define H_STR 520
#define W2FP8_OFF 229376
#define LDS_BYTES 39424

__device__ inline unsigned short f2bf(float f) {
  return __builtin_bit_cast(unsigned short, __float2bfloat16(f));
}
__device__ inline unsigned pk2bf(float lo, float hi) {
  return (unsigned)f2bf(lo) | ((unsigned)f2bf(hi) << 16);
}
__device__ inline float bf2f(unsigned short h) {
  unsigned u = ((unsigned)h) << 16;
  return __builtin_bit_cast(float, u);
}

// f32 -> fp8 e4m3fn (OCP), software fallback
__device__ inline unsigned char f2fp8_sw(float x) {
  unsigned u = __builtin_bit_cast(unsigned, x);
  unsigned sign = (u >> 31) << 7;
  float ax = fabsf(x);
  if (!(ax >= 0.015625f)) {
    int q = (int)(ax * 512.0f + 0.5f);
    if (q > 7) return (unsigned char)(sign | 8);
    return (unsigned char)(sign | q);
  }
  if (ax > 448.0f) ax = 448.0f;
  unsigned au = __builtin_bit_cast(unsigned, ax);
  int exp = (int)((au >> 23) & 0xff) - 127;
  unsigned m3 = ((au & 0x7fffff) + 0x80000) >> 20;
  if (m3 >= 8) { m3 = 0; exp += 1; }
  if (exp > 8) return (unsigned char)(sign | 0x7e);
  return (unsigned char)(sign | ((unsigned)(exp + 7) << 3) | m3);
}
__device__ inline unsigned char f2fp8(float x) {
#if defined(__has_builtin) && __has_builtin(__builtin_amdgcn_cvt_pk_fp8_f32)
  return (unsigned char)(__builtin_amdgcn_cvt_pk_fp8_f32(x, x, 0, false) & 0xff);
#else
  return f2fp8_sw(x);
#endif
}
__device__ inline unsigned pack4fp8(float a, float b, float c, float d) {
#if defined(__has_builtin) && __has_builtin(__builtin_amdgcn_cvt_pk_fp8_f32)
  int r = __builtin_amdgcn_cvt_pk_fp8_f32(a, b, 0, false);
  r = __builtin_amdgcn_cvt_pk_fp8_f32(c, d, r, true);
  return (unsigned)r;
#else
  return (unsigned)f2fp8_sw(a) | ((unsigned)f2fp8_sw(b) << 8) |
         ((unsigned)f2fp8_sw(c) << 16) | ((unsigned)f2fp8_sw(d) << 24);
#endif
}

// ---------------------------------------------------------------------------
// Pack kernel: QKV/w1 -> bf16 frags; w2 -> FP8 frags; rot table.
// ids: [0,6144) QKV | [6144,14336) w1 | [14336,22528) w2-fp8 | [22528,23040) rot
// ---------------------------------------------------------------------------
__global__ void pack_weights(const float* __restrict__ wq, const float* __restrict__ wk,
                             const float* __restrict__ wv, const float* __restrict__ w1,
                             const float* __restrict__ w2, unsigned short* __restrict__ outp)
{
  const int id = blockIdx.x * 256 + threadIdx.x;
  if (id >= 23040) return;
  if (id >= 22528) {  // rot table: (sin,cos) for (s,d)
    const int i = id - 22528;
    const int s = i >> 4, d = i & 15;
    const float a = exp2f(-1.89824462565f * (float)(d >> 1));
    const float ang = (float)s * a;
    float2* tab = (float2*)(outp + 180224);
    tab[i] = make_float2(sinf(ang), cosf(ang));
    return;
  }
  const int l = id & 63;
  const int chunk = id >> 6;
  if (chunk >= 224) {  // w2 -> fp8 B-frags, 512B/chunk
    const int c2 = chunk - 224, ct = c2 >> 4, kk = c2 & 15;
    const int colbase = ct * 16 + (l & 15);
    const int k0 = kk * 32 + (l >> 4) * 8;
    float v[8];
    #pragma unroll
    for (int jj = 0; jj < 8; ++jj) v[jj] = w2[(size_t)(k0 + jj) * CC + colbase];
    u32x2 pw;
    pw[0] = pack4fp8(v[0], v[1], v[2], v[3]);
    pw[1] = pack4fp8(v[4], v[5], v[6], v[7]);
    *(u32x2*)((char*)outp + W2FP8_OFF + ((size_t)c2 * 64 + l) * 8) = pw;
    return;
  }
  const float* W; int ldw, colbase, k0;
  if (chunk < 96) {
    const int ct = chunk >> 2, kk = chunk & 3;
    W = (ct < 8) ? wq : (ct < 16) ? wk : wv;
    ldw = CC; colbase = (ct & 7) * 16 + (l & 15); k0 = kk * 32 + (l >> 4) * 8;
  } else {
    const int c2 = chunk - 96, ct = c2 >> 2, kk = c2 & 3;
    W = w1; ldw = FF; colbase = ct * 16 + (l & 15); k0 = kk * 32 + (l >> 4) * 8;
  }
  unsigned int o[4];
  #pragma unroll
  for (int jj = 0; jj < 4; ++jj)
    o[jj] = pk2bf(W[(size_t)(k0 + 2 * jj) * ldw + colbase],
                  W[(size_t)(k0 + 2 * jj + 1) * ldw + colbase]);
  *(u32x4*)(outp + (size_t)id * 8) = (u32x4){o[0], o[1], o[2], o[3]};
}

__global__ __launch_bounds__(512, 6) void fused_mfma(
    const float* __restrict__ x,
    const float* __restrict__ bq, const float* __restrict__ bk, const float* __restrict__ bv,
    const float* __restrict__ ln1g, const float* __restrict__ ln1b,
    const float* __restrict__ b1, const float* __restrict__ b2,
    const float* __restrict__ ln2g, const float* __restrict__ ln2b,
    const unsigned short* __restrict__ wpack,
    const float2* __restrict__ rott,
    float* __restrict__ out)
{
  extern __shared__ char smem[];
  float* ldsf = (float*)smem;
  unsigned short* ldsh = (unsigned short*)smem;
  const int n = blockIdx.x;
  const int t = threadIdx.x;
  const int w = t >> 6;
  const int l = t & 63;
  const int lr = l & 15;
  const int lg = l >> 4;

  // ---------------- stage X -> bf16 LDS + rot table ------------------------
  {
    const int s = t >> 4, c0 = (t & 15) * 8;
    const float* xp = x + ((size_t)s * NN + n) * CC + c0;
    const float4 v0 = *(const float4*)xp;
    const float4 v1 = *(const float4*)(xp + 4);
    u32x4 pk;
    pk[0] = pk2bf(v0.x, v0.y);
    pk[1] = pk2bf(v0.z, v0.w);
    pk[2] = pk2bf(v1.x, v1.y);
    pk[3] = pk2bf(v1.z, v1.w);
    *(u32x4*)(ldsh + XB_H + s * 136 + c0) = pk;
    ((float2*)(ldsf + TAB_F))[t] = rott[t];
  }
  __syncthreads();

  // ---------------- QKV MFMA + fused rotary epilogue -----------------------
  {
    f32x4 acc[2][3];
    #pragma unroll
    for (int c = 0; c < 3; ++c) {
      const int ct = 3 * w + c;
      const int col = (ct & 7) * 16 + lr;
      const float* bb = (ct < 8) ? bq : (ct < 16) ? bk : bv;
      const float b = bb[col];
      acc[0][c] = (f32x4){b, b, b, b};
      acc[1][c] = acc[0][c];
    }
    #pragma unroll
    for (int kk = 0; kk < 4; ++kk) {
      const bf16x8 a0 = *(const bf16x8*)(ldsh + XB_H + lr * 136 + kk * 32 + lg * 8);
      const bf16x8 a1 = *(const bf16x8*)(ldsh + XB_H + (16 + lr) * 136 + kk * 32 + lg * 8);
      #pragma unroll
      for (int c = 0; c < 3; ++c) {
        const int ct = 3 * w + c;
        const bf16x8 b = *(const bf16x8*)(wpack + ((size_t)(ct * 4 + kk) * 64 + l) * 8);
        acc[0][c] = __builtin_amdgcn_mfma_f32_16x16x32_bf16(a0, b, acc[0][c], 0, 0, 0);
        acc[1][c] = __builtin_amdgcn_mfma_f32_16x16x32_bf16(a1, b, acc[1][c], 0, 0, 0);
      }
    }
    float sn[2][4], cs[2][4];
    if (3 * w < 16) {   // wave-uniform: only waves holding Q/K coltiles
      #pragma unroll
      for (int rt = 0; rt < 2; ++rt)
        #pragma unroll
        for (int e = 0; e < 4; ++e) {
          const int row = rt * 16 + lg * 4 + e;
          const float2 tc = ((const float2*)(ldsf + TAB_F))[row * 16 + lr];
          sn[rt][e] = tc.x;
          cs[rt][e] = tc.y;
        }
    }
    const int pd = (lr < 8) ? (2 * lr + 1) : (2 * lr - 16);
    const float sgn = (lr < 8) ? -1.0f : 1.0f;
    const int psrc = (l & 48) | pd;
    #pragma unroll
    for (int c = 0; c < 3; ++c) {
      const int ct = 3 * w + c;
      if (ct < 16) {
        const int dst = (ct < 8) ? QB_H : KB_H;
        const int colbase = (ct & 7) * 16;
        #pragma unroll
        for (int rt = 0; rt < 2; ++rt)
          #pragma unroll
          for (int e = 0; e < 4; ++e) {
            const float v = acc[rt][c][e];
            const float pv = __shfl(v, psrc);
            const float r = v * cs[rt][e] + sgn * pv * sn[rt][e];
            ldsh[dst + (rt * 16 + lg * 4 + e) * 136 + colbase + lr] = f2bf(r);
          }
      } else {
        // V^T: head hv, VT[hv][d=lr][s], stride 36 (bank-spread)
        const int hv = ct - 16;
        #pragma unroll
        for (int rt = 0; rt < 2; ++rt)
          #pragma unroll
          for (int e = 0; e < 4; ++e)
            ldsh[VT_H + hv * 576 + lr * 36 + rt * 16 + lg * 4 + e] = f2bf(acc[rt][c][e]);
      }
    }
  }
  __syncthreads();

  // ---------------- MFMA attention: wave w = head w ------------------------
  {
    const int h16 = w * 16;
    const float dec = log1pf(-exp2f(-(1.0f + 0.375f * (float)w)));
    const bf16x8 z = {};
    bf16x8 Ak[2], Bq[2];
    #pragma unroll
    for (int kt = 0; kt < 2; ++kt)
      Ak[kt] = (lg < 2) ? *(const bf16x8*)(ldsh + KB_H + (kt * 16 + lr) * 136 + h16 + lg * 8) : z;
    #pragma unroll
    for (int qt = 0; qt < 2; ++qt)
      Bq[qt] = (lg < 2) ? *(const bf16x8*)(ldsh + QB_H + (qt * 16 + lr) * 136 + h16 + lg * 8) : z;
    const bf16x8 Bv = *(const bf16x8*)(ldsh + VT_H + w * 576 + lr * 36 + lg * 8);
    __syncthreads();   // frags in regs; QB/KB/VT now reusable as P; OO writable

    f32x4 accs[2][2];
    #pragma unroll
    for (int kt = 0; kt < 2; ++kt)
      #pragma unroll
      for (int qt = 0; qt < 2; ++qt) {
        #pragma unroll
        for (int e = 0; e < 4; ++e) {
          const int q = qt * 16 + lr;
          const int k = kt * 16 + lg * 4 + e;
          accs[kt][qt][e] = fabsf((float)(q - k)) * dec;
        }
        accs[kt][qt] = __builtin_amdgcn_mfma_f32_16x16x32_bf16(Ak[kt], Bq[qt], accs[kt][qt], 0, 0, 0);
      }
    unsigned short* Pl = ldsh + P_H + w * P_HEAD;
    #pragma unroll
    for (int qt = 0; qt < 2; ++qt) {
      float mx = accs[0][qt][0];
      #pragma unroll
      for (int kt = 0; kt < 2; ++kt)
        #pragma unroll
        for (int e = 0; e < 4; ++e) mx = fmaxf(mx, accs[kt][qt][e]);
      mx = fmaxf(mx, __shfl_xor(mx, 16));
      mx = fmaxf(mx, __shfl_xor(mx, 32));
      float p[2][4];
      float sm = 0.0f;
      #pragma unroll
      for (int kt = 0; kt < 2; ++kt)
        #pragma unroll
        for (int e = 0; e < 4; ++e) { p[kt][e] = __expf(accs[kt][qt][e] - mx); sm += p[kt][e]; }
      sm += __shfl_xor(sm, 16);
      sm += __shfl_xor(sm, 32);
      const float inv = 1.0f / sm;
      #pragma unroll
      for (int kt = 0; kt < 2; ++kt) {
        u32x2 pw;
        pw[0] = pk2bf(p[kt][0] * inv, p[kt][1] * inv);
        pw[1] = pk2bf(p[kt][2] * inv, p[kt][3] * inv);
        *(u32x2*)(Pl + (qt * 16 + lr) * P_STR + kt * 16 + lg * 4) = pw;
      }
    }
    // PV: Bv preloaded; attn-out -> OO region
    #pragma unroll
    for (int qt = 0; qt < 2; ++qt) {
      const bf16x8 Ap = *(const bf16x8*)(Pl + (qt * 16 + lr) * P_STR + lg * 8);
      f32x4 z4 = {0.0f, 0.0f, 0.0f, 0.0f};
      const f32x4 o = __builtin_amdgcn_mfma_f32_16x16x32_bf16(Ap, Bv, z4, 0, 0, 0);
      #pragma unroll
      for (int e = 0; e < 4; ++e)
        ldsh[OO_H + (qt * 16 + lg * 4 + e) * 136 + h16 + lr] = f2bf(o[e]);
    }
  }
  __syncthreads();

  // ---------------- LN1(attn_out + x) -> bf16, in place over OO ------------
  {
    const int row = t >> 4, sub = t & 15;
    const unsigned short* Or = ldsh + OO_H + row * 136 + sub * 8;
    const unsigned short* Xr = ldsh + XB_H + row * 136 + sub * 8;
    float v[8];
    #pragma unroll
    for (int i = 0; i < 8; ++i) v[i] = bf2f(Or[i]) + bf2f(Xr[i]);
    float sum = 0.0f;
    #pragma unroll
    for (int i = 0; i < 8; ++i) sum += v[i];
    #pragma unroll
    for (int m = 1; m < 16; m <<= 1) sum += __shfl_xor(sum, m);
    const float mu = sum * (1.0f / 128.0f);
    float s2 = 0.0f;
    #pragma unroll
    for (int i = 0; i < 8; ++i) { const float d = v[i] - mu; s2 += d * d; }
    #pragma unroll
    for (int m = 1; m < 16; m <<= 1) s2 += __shfl_xor(s2, m);
    const float rstd = rsqrtf(s2 * (1.0f / 128.0f) + 1e-5f);
    u32x4 pk;
    #pragma unroll
    for (int i = 0; i < 4; ++i) {
      const int c = sub * 8 + 2 * i;
      pk[i] = pk2bf((v[2 * i] - mu) * rstd * ln1g[c] + ln1b[c],
                    (v[2 * i + 1] - mu) * rstd * ln1g[c + 1] + ln1b[c + 1]);
    }
    *(u32x4*)(ldsh + OO_H + row * 136 + sub * 8) = pk;   // same addrs this thread read
  }
  __syncthreads();

  // ---------------- FFN1: H fp8[32][520] = relu(O1 @ w1 + b1) --------------
  {
    f32x4 acc1[2][4];
    #pragma unroll
    for (int c = 0; c < 4; ++c) {
      const float b = b1[(4 * w + c) * 16 + lr];
      acc1[0][c] = (f32x4){b, b, b, b};
      acc1[1][c] = acc1[0][c];
    }
    #pragma unroll
    for (int kk = 0; kk < 4; ++kk) {
      const bf16x8 a0 = *(const bf16x8*)(ldsh + OO_H + lr * 136 + kk * 32 + lg * 8);
      const bf16x8 a1 = *(const bf16x8*)(ldsh + OO_H + (16 + lr) * 136 + kk * 32 + lg * 8);
      #pragma unroll
      for (int c = 0; c < 4; ++c) {
        const int chunk = 96 + (4 * w + c) * 4 + kk;
        const bf16x8 b = *(const bf16x8*)(wpack + ((size_t)chunk * 64 + l) * 8);
        acc1[0][c] = __builtin_amdgcn_mfma_f32_16x16x32_bf16(a0, b, acc1[0][c], 0, 0, 0);
        acc1[1][c] = __builtin_amdgcn_mfma_f32_16x16x32_bf16(a1, b, acc1[1][c], 0, 0, 0);
      }
    }
    char* Hb = smem;   // H over dead XB/QB, [0,16640)
    #pragma unroll
    for (int p = 0; p < 2; ++p)
      #pragma unroll
      for (int c = 0; c < 4; ++c) {
        const int col = (4 * w + c) * 16 + lr;
        #pragma unroll
        for (int e = 0; e < 4; ++e) {
          const int row = p * 16 + lg * 4 + e;
          Hb[row * H_STR + col] = (char)f2fp8(fmaxf(acc1[p][c][e], 0.0f));
        }
      }
  }
  __syncthreads();

  // ---------------- FFN2 (fp8): O2 = H @ w2 + b2 + O1, in place over OO ----
  {
    const int col = w * 16 + lr;
    const float b = b2[col];
    f32x4 acc2[2];
    acc2[0] = (f32x4){b, b, b, b};
    acc2[1] = acc2[0];
    const char* Hb = smem;
    const char* W2 = (const char*)wpack + W2FP8_OFF;
    #pragma unroll
    for (int kk = 0; kk < 16; ++kk) {
      const long a0 = *(const long*)(Hb + lr * H_STR + kk * 32 + lg * 8);
      const long a1 = *(const long*)(Hb + (16 + lr) * H_STR + kk * 32 + lg * 8);
      const long bb = *(const long*)(W2 + ((size_t)(w * 16 + kk) * 64 + l) * 8);
      acc2[0] = __builtin_amdgcn_mfma_f32_16x16x32_fp8_fp8(a0, bb, acc2[0], 0, 0, 0);
      acc2[1] = __builtin_amdgcn_mfma_f32_16x16x32_fp8_fp8(a1, bb, acc2[1], 0, 0, 0);
    }
    #pragma unroll
    for (int p = 0; p < 2; ++p)
      #pragma unroll
      for (int e = 0; e < 4; ++e) {
        const int srow = p * 16 + lg * 4 + e;
        const int idx = OO_H + srow * 136 + col;
        const float res = bf2f(ldsh[idx]);                 // same-thread RAW, safe
        ldsh[idx] = f2bf(acc2[p][e] + res);
      }
  }
  __syncthreads();

  // ---------------- LN2 (32 rows at once) + transposed store ---------------
  {
    const int row = t >> 4, sub = t & 15;
    const unsigned short* Or = ldsh + OO_H + row * 136 + sub * 8;
    float v[8];
    #pragma unroll
    for (int i = 0; i < 8; ++i) v[i] = bf2f(Or[i]);
    float sum = 0.0f;
    #pragma unroll
    for (int i = 0; i < 8; ++i) sum += v[i];
    #pragma unroll
    for (int m = 1; m < 16; m <<= 1) sum += __shfl_xor(sum, m);
    const float mu = sum * (1.0f / 128.0f);
    float s2 = 0.0f;
    #pragma unroll
    for (int i = 0; i < 8; ++i) { const float d = v[i] - mu; s2 += d * d; }
    #pragma unroll
    for (int m = 1; m < 16; m <<= 1) s2 += __shfl_xor(s2, m);
    const float rstd = rsqrtf(s2 * (1.0f / 128.0f) + 1e-5f);
    const int c0 = sub * 8;
    float4 r0, r1;
    r0.x = (v[0] - mu) * rstd * ln2g[c0 + 0] + ln2b[c0 + 0];
    r0.y = (v[1] - mu) * rstd * ln2g[c0 + 1] + ln2b[c0 + 1];
    r0.z = (v[2] - mu) * rstd * ln2g[c0 + 2] + ln2b[c0 + 2];
    r0.w = (v[3] - mu) * rstd * ln2g[c0 + 3] + ln2b[c0 + 3];
    r1.x = (v[4] - mu) * rstd * ln2g[c0 + 4] + ln2b[c0 + 4];
    r1.y = (v[5] - mu) * rstd * ln2g[c0 + 5] + ln2b[c0 + 5];
    r1.z = (v[6] - mu) * rstd * ln2g[c0 + 6] + ln2b[c0 + 6];
    r1.w = (v[7] - mu) * rstd * ln2g[c0 + 7] + ln2b[c0 + 7];
    float* op = out + ((size_t)row * NN + n) * CC + c0;
    *(float4*)op = r0;
    *(float4*)(op + 4) = r1;
  }
}

// ---------------------------------------------------------------------------
// Fallback: round-1 fp32 kernel if ws too small for packing (never expected).
// ---------------------------------------------------------------------------
__global__ __launch_bounds__(512, 4) void fused_retention_block(
    const float* __restrict__ x,
    const float* __restrict__ wq, const float* __restrict__ bq,
    const float* __restrict__ wk, const float* __restrict__ bk,
    const float* __restrict__ wv, const float* __restrict__ bv,
    const float* __restrict__ ln1g, const float* __restrict__ ln1b,
    const float* __restrict__ w1, const float* __restrict__ b1,
    const float* __restrict__ w2, const float* __restrict__ b2,
    const float* __restrict__ ln2g, const float* __restrict__ ln2b,
    float* __restrict__ out)
{
  const int n = blockIdx.x;
  const int t = threadIdx.x;
  __shared__ float SM[3 * BS * QS];
  float* Qs = SM;
  float* Ks = SM + BS * QS;
  float* Vs = SM + 2 * BS * QS;
  {
    const int o4 = t & 31;
    const int sp = t >> 5;
    const float* xr0 = x + ((size_t)(2 * sp) * NN + n) * CC;
    const float* xr1 = xr0 + (size_t)NN * CC;
    for (int m = 0; m < 3; ++m) {
      const float* W  = (m == 0) ? wq : (m == 1) ? wk : wv;
      const float* bb = (m == 0) ? bq : (m == 1) ? bk : bv;
      float* O = SM + m * BS * QS;
      float b4[4];
      *(float4*)b4 = *(const float4*)(bb + o4 * 4);
      float a0[4] = {b4[0], b4[1], b4[2], b4[3]};
      float a1[4] = {b4[0], b4[1], b4[2], b4[3]};
      for (int c4 = 0; c4 < 32; ++c4) {
        float xa4[4], xb4[4];
        *(float4*)xa4 = *(const float4*)(xr0 + c4 * 4);
        *(float4*)xb4 = *(const float4*)(xr1 + c4 * 4);
        const float* wp = W + (c4 * 4) * CC + o4 * 4;
        #pragma unroll
        for (int j = 0; j < 4; ++j) {
          float w4[4];
          *(float4*)w4 = *(const float4*)(wp + j * CC);
          #pragma unroll
          for (int e = 0; e < 4; ++e) { a0[e] += xa4[j] * w4[e]; a1[e] += xb4[j] * w4[e]; }
        }
      }
      float* q0 = O + (2 * sp) * QS + o4 * 4;
      float* q1 = O + (2 * sp + 1) * QS + o4 * 4;
      #pragma unroll
      for (int e = 0; e < 4; ++e) { q0[e] = a0[e]; q1[e] = a1[e]; }
    }
  }
  __syncthreads();
  {
    const int tt = t & 255;
    const int s = tt >> 3;
    const int h = tt & 7;
    float* row = ((t < 256) ? Qs : Ks) + s * QS + h * DD;
    float v[DD];
    #pragma unroll
    for (int d = 0; d < DD; ++d) v[d] = row[d];
    #pragma unroll
    for (int d = 0; d < DD; ++d) {
      const int j = d >> 1;
      const float a = exp2f(-1.89824462565f * (float)j);
      const float ang = (float)s * a;
      const float sn = sinf(ang);
      const float cs = cosf(ang);
      const float rot = (d < 8) ? -v[2 * d + 1] : v[2 * (d - 8)];
      row[d] = v[d] * cs + rot * sn;
    }
  }
  __syncthreads();
  if (t < 256) {
    const int h = t >> 5;
    const int qi = t & 31;
    const float dec = log1pf(-exp2f(-(1.0f + 0.375f * (float)h)));
    float q[DD];
    const float* Qr = Qs + qi * QS + h * DD;
    #pragma unroll
    for (int d = 0; d < DD; ++d) q[d] = Qr[d];
    float sc[BS];
    float mx = -3.0e38f;
    #pragma unroll
    for (int jj = 0; jj < BS; ++jj) {
      const float* Kr = Ks + jj * QS + h * DD;
      float acc = fabsf((float)(qi - jj)) * dec;
      #pragma unroll
      for (int d = 0; d < DD; ++d) acc += q[d] * Kr[d];
      sc[jj] = acc;
      mx = fmaxf(mx, acc);
    }
    float sum = 0.0f;
    #pragma unroll
    for (int jj = 0; jj < BS; ++jj) { const float p = __expf(sc[jj] - mx); sc[jj] = p; sum += p; }
    const float inv = 1.0f / sum;
    float o[DD];
    #pragma unroll
    for (int d = 0; d < DD; ++d) o[d] = 0.0f;
    #pragma unroll
    for (int jj = 0; jj < BS; ++jj) {
      const float p = sc[jj] * inv;
      const float* Vr = Vs + jj * QS + h * DD;
      #pragma unroll
      for (int d = 0; d < DD; ++d) o[d] += p * Vr[d];
    }
    float* Od = Qs + qi * QS + h * DD;
    #pragma unroll
    for (int d = 0; d < DD; ++d) Od[d] = o[d];
  }
  __syncthreads();
  {
    const int row = t >> 4;
    const int sub = t & 15;
    float* Orow = Qs + row * QS + sub * 8;
    const float* xrow = x + ((size_t)row * NN + n) * CC + sub * 8;
    float v[8];
    #pragma unroll
    for (int i = 0; i < 8; ++i) v[i] = Orow[i] + xrow[i];
    float sum = 0.0f;
    #pragma unroll
    for (int i = 0; i < 8; ++i) sum += v[i];
    #pragma unroll
    for (int m = 1; m < 16; m <<= 1) sum += __shfl_xor(sum, m);
    const float mu = sum * (1.0f / 128.0f);
    float s2 = 0.0f;
    #pragma unroll
    for (int i = 0; i < 8; ++i) { const float d = v[i] - mu; s2 += d * d; }
    #pragma unroll
    for (int m = 1; m < 16; m <<= 1) s2 += __shfl_xor(s2, m);
    const float rstd = rsqrtf(s2 * (1.0f / 128.0f) + 1e-5f);
    #pragma unroll
    for (int i = 0; i < 8; ++i) {
      const int c = sub * 8 + i;
      Orow[i] = (v[i] - mu) * rstd * ln1g[c] + ln1b[c];
    }
  }
  __syncthreads();
  float* Hb = Ks;
  const int f4  = t & 127;
  const int sb4 = (t >> 7) * 4;
  const int o4f = t & 31;
  const int sF  = t >> 5;
  for (int p = 0; p < 2; ++p) {
    {
      float acc[4][4];
      float b14[4];
      *(float4*)b14 = *(const float4*)(b1 + f4 * 4);
      #pragma unroll
      for (int i = 0; i < 4; ++i)
        #pragma unroll
        for (int e = 0; e < 4; ++e) acc[i][e] = b14[e];
      const float* O1b = Qs + (p * 16 + sb4) * QS;
      for (int c = 0; c < CC; ++c) {
        float w4[4];
        *(float4*)w4 = *(const float4*)(w1 + c * FF + f4 * 4);
        #pragma unroll
        for (int i = 0; i < 4; ++i) {
          const float xv = O1b[i * QS + c];
          #pragma unroll
          for (int e = 0; e < 4; ++e) acc[i][e] += xv * w4[e];
        }
      }
      #pragma unroll
      for (int i = 0; i < 4; ++i) {
        float4 r;
        r.x = fmaxf(acc[i][0], 0.0f); r.y = fmaxf(acc[i][1], 0.0f);
        r.z = fmaxf(acc[i][2], 0.0f); r.w = fmaxf(acc[i][3], 0.0f);
        *(float4*)(Hb + (sb4 + i) * FF + f4 * 4) = r;
      }
    }
    __syncthreads();
    {
      const int s = p * 16 + sF;
      float acc[4];
      *(float4*)acc = *(const float4*)(b2 + o4f * 4);
      const float* hrow = Hb + sF * FF;
      for (int k = 0; k < FF; ++k) {
        const float hv = hrow[k];
        float w4[4];
        *(float4*)w4 = *(const float4*)(w2 + k * CC + o4f * 4);
        #pragma unroll
        for (int e = 0; e < 4; ++e) acc[e] += hv * w4[e];
      }
      const float* res = Qs + s * QS + o4f * 4;
      #pragma unroll
      for (int e = 0; e < 4; ++e) acc[e] += res[e];
      float sum = acc[0] + acc[1] + acc[2] + acc[3];
      #pragma unroll
      for (int m = 1; m < 32; m <<= 1) sum += __shfl_xor(sum, m);
      const float mu = sum * (1.0f / 128.0f);
      float s2 = 0.0f;
      #pragma unroll
      for (int e = 0; e < 4; ++e) { const float d = acc[e] - mu; s2 += d * d; }
      #pragma unroll
      for (int m = 1; m < 32; m <<= 1) s2 += __shfl_xor(s2, m);
      const float rstd = rsqrtf(s2 * (1.0f / 128.0f) + 1e-5f);
      float4 r;
      const int c0 = o4f * 4;
      r.x = (acc[0] - mu) * rstd * ln2g[c0 + 0] + ln2b[c0 + 0];
      r.y = (acc[1] - mu) * rstd * ln2g[c0 + 1] + ln2b[c0 + 1];
      r.z = (acc[2] - mu) * rstd * ln2g[c0 + 2] + ln2b[c0 + 2];
      r.w = (acc[3] - mu) * rstd * ln2g[c0 + 3] + ln2b[c0 + 3];
      *(float4*)(out + ((size_t)s * NN + n) * CC + c0) = r;
    }
    __syncthreads();
  }
}

extern "C" void kernel_launch(void* const* d_in, const int* in_sizes, int n_in,
                              void* d_out, int out_size, void* d_ws, size_t ws_size,
                              hipStream_t stream) {
  (void)in_sizes; (void)n_in; (void)out_size;
  const float* x    = (const float*)d_in[0];
  const float* wq   = (const float*)d_in[1];
  const float* bq_  = (const float*)d_in[2];
  const float* wk   = (const float*)d_in[3];
  const float* bk_  = (const float*)d_in[4];
  const float* wv   = (const float*)d_in[5];
  const float* bv_  = (const float*)d_in[6];
  const float* ln1g = (const float*)d_in[7];
  const float* ln1b = (const float*)d_in[8];
  const float* w1   = (const float*)d_in[9];
  const float* b1   = (const float*)d_in[10];
  const float* w2   = (const float*)d_in[11];
  const float* b2   = (const float*)d_in[12];
  const float* ln2g = (const float*)d_in[13];
  const float* ln2b = (const float*)d_in[14];
  float* outp = (float*)d_out;

  if (ws_size >= (size_t)364544) {
    unsigned short* wpack = (unsigned short*)d_ws;
    const float2* rott = (const float2*)((const char*)d_ws + 360448);
    pack_weights<<<90, 256, 0, stream>>>(wq, wk, wv, w1, w2, wpack);
    fused_mfma<<<NN, 512, LDS_BYTES, stream>>>(
        x, bq_, bk_, bv_, ln1g, ln1b, b1, b2, ln2g, ln2b, wpack, rott, outp);
  } else {
    fused_retention_block<<<NN, 512, 0, stream>>>(
        x, wq, bq_, wk, bk_, wv, bv_, ln1g, ln1b,
        w1, b1, w2, b2, ln2g, ln2b, outp);
  }
}